// Round 7
// baseline (436.085 us; speedup 1.0000x reference)
//
#include <hip/hip_runtime.h>

#define N_K 20000
#define N_E 50000
#define N_U 100000
#define E_UND 200000
#define E_EK 400000
#define E_EU 600000
#define E_TOT 2200000
#define N_TOT 240000
// padded (64-aligned) agg-row segment bases: GAT1 kn | GAT2 kn | GAT3 exer | GAT4 stu | GAT5 exer
#define PB1 0
#define PB2 20032
#define PB3 40064
#define PB4 90112
#define PB5 190144
#define PTOT 240192
// key-space (concat dst) bases — also the erc concat layout
#define KB1 0
#define KB2 20000
#define KB3 40000
#define KB4 90000
#define KB5 190000

typedef unsigned short u16;
typedef unsigned int u32;
typedef __bf16 bf16x8 __attribute__((ext_vector_type(8)));
typedef float f32x4 __attribute__((ext_vector_type(4)));

__device__ __forceinline__ float bf2f(u16 v){
    union { u32 u; float f; } x; x.u = ((u32)v) << 16; return x.f;
}
__device__ __forceinline__ u16 f2bf(float f){
    union { float f; u32 u; } x; x.f = f;
    u32 r = x.u + 0x7FFFu + ((x.u >> 16) & 1u);
    return (u16)(r >> 16);
}
__device__ __forceinline__ float leaky_exp(float x){
    x = x >= 0.f ? x : 0.01f*x;
    return __expf(x);
}

// ---------------------------------------------------------------- prep: wl/wr
__global__ void prep_vecs(const float* W0, const float* W1, const float* W2, const float* W3, const float* W4,
                          const float* a0, const float* a1, const float* a2, const float* a3, const float* a4,
                          float* __restrict__ vecs)
{
    int b = blockIdx.x;          // 0..9
    int g = b % 5, which = b / 5;
    const float* W = g==0?W0:g==1?W1:g==2?W2:g==3?W3:W4;
    const float* a = g==0?a0:g==1?a1:g==2?a2:g==3?a3:a4;
    const float* av = a + which*128;
    int k = threadIdx.x;         // 0..127
    float sum = 0.f;
    for (int c = 0; c < 128; ++c)
        sum += W[k*128 + c] * av[c];
    vecs[(which*5 + g)*128 + k] = sum;
}

// -------------------------------------------- W -> MFMA-B-fragment order (bf16)
__global__ void fragify(const float* W0, const float* W1, const float* W2, const float* W3, const float* W4,
                        u16* __restrict__ Wf)
{
    int g = blockIdx.x;
    const float* W = g==0?W0:g==1?W1:g==2?W2:g==3?W3:W4;
    u16* out = Wf + g*16384;
    for (int i = threadIdx.x; i < 2048; i += blockDim.x){
        int lane = i & 63, t = i >> 6, ks = t & 3, ct = t >> 2;
        int kbase = ks*32 + (lane>>4)*8;
        int c = ct*16 + (lane&15);
        #pragma unroll
        for (int j = 0; j < 8; ++j)
            out[i*8 + j] = f2bf(W[(kbase+j)*128 + c]);
    }
}

// ------------------------------------------------- fused conv(f32->bf16) + row dots
template<int ND, int WBF>
__global__ __launch_bounds__(256) void conv_dot(const float* __restrict__ h, u16* __restrict__ hb,
    const float* __restrict__ v0, const float* __restrict__ v1,
    const float* __restrict__ v2, const float* __restrict__ v3,
    float* __restrict__ o0, float* __restrict__ o1,
    float* __restrict__ o2, float* __restrict__ o3, int nrows)
{
    int w = (int)((blockIdx.x*(u32)blockDim.x + threadIdx.x) >> 6);
    int lane = threadIdx.x & 63;
    if (w >= nrows) return;
    float2 hv = *(const float2*)(h + (size_t)w*128 + lane*2);
    if (WBF)
        *(u32*)(hb + (size_t)w*128 + lane*2) = (u32)f2bf(hv.x) | ((u32)f2bf(hv.y) << 16);
    int c = lane*2;
    float d0 = hv.x*v0[c] + hv.y*v0[c+1];
    float d1 = hv.x*v1[c] + hv.y*v1[c+1];
    float d2 = 0.f, d3 = 0.f;
    if (ND == 4){
        d2 = hv.x*v2[c] + hv.y*v2[c+1];
        d3 = hv.x*v3[c] + hv.y*v3[c+1];
    }
    #pragma unroll
    for (int o = 32; o; o >>= 1){
        d0 += __shfl_xor(d0, o); d1 += __shfl_xor(d1, o);
        if (ND == 4){ d2 += __shfl_xor(d2, o); d3 += __shfl_xor(d3, o); }
    }
    if (lane == 0){
        o0[w] = d0; o1[w] = d1;
        if (ND == 4){ o2[w] = d2; o3[w] = d3; }
    }
}

// ------------------------------------------------- CSR build (all 5 graphs fused)
__global__ void count_all(const int* __restrict__ ud,
                          const int* __restrict__ es, const int* __restrict__ ed,
                          const int* __restrict__ vs, const int* __restrict__ vd,
                          int* __restrict__ cnt)
{
    int e = blockIdx.x*256 + threadIdx.x;
    if (e >= E_TOT) return;
    int dstv, nb;
    if (e < 200000){ dstv = ud[e]; nb = KB1; }
    else if (e < 600000){ dstv = ed[e-200000]; nb = KB2; }
    else if (e < 1000000){ dstv = es[e-600000]; nb = KB3; }
    else if (e < 1600000){ dstv = vd[e-1000000]; nb = KB4; }
    else { dstv = vs[e-1600000]; nb = KB5; }
    atomicAdd(&cnt[nb + dstv], 1);
}

// range-partitioned fill+edge-weight (r5): keys in [klo,khi) only -> L2-hot slices.
__global__ void fill_ev(const int* __restrict__ us, const int* __restrict__ ud,
                        const int* __restrict__ es, const int* __restrict__ ed,
                        const int* __restrict__ vs, const int* __restrict__ vd,
                        const float* __restrict__ el1, const float* __restrict__ el2,
                        const float* __restrict__ el3, const float* __restrict__ el4,
                        const float* __restrict__ el5, const float* __restrict__ erc,
                        int* __restrict__ cur, int2* __restrict__ sorted2,
                        int klo, int khi)
{
    int e = blockIdx.x*256 + threadIdx.x;
    if (e >= E_TOT) return;
    int dstv, nb;
    if (e < 200000){ dstv = ud[e]; nb = KB1; }
    else if (e < 600000){ dstv = ed[e-200000]; nb = KB2; }
    else if (e < 1000000){ dstv = es[e-600000]; nb = KB3; }
    else if (e < 1600000){ dstv = vd[e-1000000]; nb = KB4; }
    else { dstv = vs[e-1600000]; nb = KB5; }
    int key = nb + dstv;
    if (key < klo || key >= khi) return;
    int srcv; const float* el;
    if (e < 200000){ srcv = us[e]; el = el1; }
    else if (e < 600000){ srcv = es[e-200000]; el = el2; }
    else if (e < 1000000){ srcv = ed[e-600000]; el = el3; }
    else if (e < 1600000){ srcv = vs[e-1000000]; el = el4; }
    else { srcv = vd[e-1600000]; el = el5; }
    float ev = leaky_exp(el[srcv] + erc[key]);
    int pos = atomicAdd(&cur[key], 1);
    sorted2[pos] = make_int2(srcv, __float_as_int(ev));
}

// block-level exclusive scan (Hillis-Steele in LDS)
__global__ void scan1(const int* __restrict__ cnt, int* __restrict__ off, int* __restrict__ bsum, int n){
    __shared__ int sm[256];
    int t = threadIdx.x;
    int i = blockIdx.x*256 + t;
    int v = (i < n) ? cnt[i] : 0;
    sm[t] = v; __syncthreads();
    #pragma unroll
    for (int d = 1; d < 256; d <<= 1){
        int x = (t >= d) ? sm[t-d] : 0;
        __syncthreads();
        sm[t] += x;
        __syncthreads();
    }
    if (i < n) off[i] = sm[t] - v;
    if (t == 255) bsum[blockIdx.x] = sm[255];
}

__global__ void scan2(int* __restrict__ bsum, int nb){
    __shared__ int sm[1024];
    int t = threadIdx.x;
    int v = (t < nb) ? bsum[t] : 0;
    sm[t] = v; __syncthreads();
    #pragma unroll
    for (int d = 1; d < 1024; d <<= 1){
        int x = (t >= d) ? sm[t-d] : 0;
        __syncthreads();
        sm[t] += x;
        __syncthreads();
    }
    if (t < nb) bsum[t] = sm[t] - v;
}

__global__ void scan3(int* __restrict__ off, int* __restrict__ cur, const int* __restrict__ bsum, int n){
    int i = blockIdx.x*256 + threadIdx.x;
    if (i < n){
        int v = off[i] + bsum[blockIdx.x];
        off[i] = v;
        cur[i] = v;
    }
}

// ------------------------------------------------- fused GAT aggregation
// Split-wave layout (r7): 32 lanes per edge-row (8B/lane), 2 edges per wave.
// Halves accumulate disjoint edge subsets of the SAME dst row; merged by
// shfl_xor(32) at the end. Halves per-edge VALU and doubles gathers in flight.
template<int BF>
__global__ __launch_bounds__(256) void aggregate_all(
    const int* __restrict__ cnt, const int* __restrict__ off, const int2* __restrict__ sorted2,
    const void* __restrict__ hk, const void* __restrict__ he, const void* __restrict__ hs,
    u16* __restrict__ agg)
{
    int row = (int)((blockIdx.x*(u32)blockDim.x + threadIdx.x) >> 6);
    int lane = threadIdx.x & 63;
    int half = lane >> 5, sub = lane & 31;
    if (row >= PTOT) return;
    int local, nb, sn;
    const void* h;
    if (row < PB2){ local=row;      nb=KB1; sn=N_K; h=hk; }
    else if (row < PB3){ local=row-PB2; nb=KB2; sn=N_K; h=he; }
    else if (row < PB4){ local=row-PB3; nb=KB3; sn=N_E; h=hk; }
    else if (row < PB5){ local=row-PB4; nb=KB4; sn=N_U; h=he; }
    else {              local=row-PB5; nb=KB5; sn=N_E; h=hs; }
    if (local >= sn) return;   // 64-pad tail
    int ci = nb + local;
    int deg = cnt[ci], start = off[ci];
    float a0=0.f, a1=0.f, a2=0.f, a3=0.f, ssum=0.f;
    const u32* hb32 = (const u32*)h;      // bf16 row = 64 u32
    const float4* hf4 = (const float4*)h; // f32 row  = 32 float4
    int i = 0;
    for (; i + 8 <= deg; i += 8){          // 4 edges per half per iter
        int2 w[4];
        #pragma unroll
        for (int j = 0; j < 4; ++j) w[j] = sorted2[start + i + 2*j + half];
        if (BF){
            uint2 hv[4];
            #pragma unroll
            for (int j = 0; j < 4; ++j) hv[j] = *(const uint2*)(hb32 + (size_t)w[j].x*64 + sub*2);
            #pragma unroll
            for (int j = 0; j < 4; ++j){
                float ev = __int_as_float(w[j].y);
                a0 = fmaf(ev, bf2f((u16)hv[j].x), a0);
                a1 = fmaf(ev, bf2f((u16)(hv[j].x>>16)), a1);
                a2 = fmaf(ev, bf2f((u16)hv[j].y), a2);
                a3 = fmaf(ev, bf2f((u16)(hv[j].y>>16)), a3);
                ssum += ev;
            }
        } else {
            float4 hv[4];
            #pragma unroll
            for (int j = 0; j < 4; ++j) hv[j] = hf4[(size_t)w[j].x*32 + sub];
            #pragma unroll
            for (int j = 0; j < 4; ++j){
                float ev = __int_as_float(w[j].y);
                a0 = fmaf(ev, hv[j].x, a0);
                a1 = fmaf(ev, hv[j].y, a1);
                a2 = fmaf(ev, hv[j].z, a2);
                a3 = fmaf(ev, hv[j].w, a3);
                ssum += ev;
            }
        }
    }
    for (; i + 2 <= deg; i += 2){          // 1 edge per half
        int2 w = sorted2[start + i + half];
        float ev = __int_as_float(w.y);
        if (BF){
            uint2 hv = *(const uint2*)(hb32 + (size_t)w.x*64 + sub*2);
            a0 = fmaf(ev, bf2f((u16)hv.x), a0);
            a1 = fmaf(ev, bf2f((u16)(hv.x>>16)), a1);
            a2 = fmaf(ev, bf2f((u16)hv.y), a2);
            a3 = fmaf(ev, bf2f((u16)(hv.y>>16)), a3);
        } else {
            float4 hv = hf4[(size_t)w.x*32 + sub];
            a0 = fmaf(ev, hv.x, a0); a1 = fmaf(ev, hv.y, a1);
            a2 = fmaf(ev, hv.z, a2); a3 = fmaf(ev, hv.w, a3);
        }
        ssum += ev;
    }
    if (i < deg && half == 0){             // odd tail: half 0 only
        int2 w = sorted2[start + i];
        float ev = __int_as_float(w.y);
        if (BF){
            uint2 hv = *(const uint2*)(hb32 + (size_t)w.x*64 + sub*2);
            a0 = fmaf(ev, bf2f((u16)hv.x), a0);
            a1 = fmaf(ev, bf2f((u16)(hv.x>>16)), a1);
            a2 = fmaf(ev, bf2f((u16)hv.y), a2);
            a3 = fmaf(ev, bf2f((u16)(hv.y>>16)), a3);
        } else {
            float4 hv = hf4[(size_t)w.x*32 + sub];
            a0 = fmaf(ev, hv.x, a0); a1 = fmaf(ev, hv.y, a1);
            a2 = fmaf(ev, hv.z, a2); a3 = fmaf(ev, hv.w, a3);
        }
        ssum += ev;
    }
    // merge halves
    a0 += __shfl_xor(a0, 32); a1 += __shfl_xor(a1, 32);
    a2 += __shfl_xor(a2, 32); a3 += __shfl_xor(a3, 32);
    ssum += __shfl_xor(ssum, 32);
    float inv = (ssum > 0.f) ? 1.f/ssum : 0.f;   // deg==0 -> zero row
    if (half == 0){
        u32 p0 = (u32)f2bf(a0*inv) | ((u32)f2bf(a1*inv) << 16);
        u32 p1 = (u32)f2bf(a2*inv) | ((u32)f2bf(a3*inv) << 16);
        *(uint2*)(agg + (size_t)row*128 + sub*4) = make_uint2(p0, p1);
    }
}

// ------------------------------------------------- fused dual-GEMM + gating epilogue
// BF=1: A (residual/gating input) read from bf16 copies — halves A traffic.
#define KBLK 313
#define EBLK 782
#define SBLK 1563
template<int BF>
__global__ __launch_bounds__(256) void gemm_epi(const u16* __restrict__ agg, const u16* __restrict__ Wf,
    const void* __restrict__ knA, const void* __restrict__ exerA, const void* __restrict__ stuA,
    const float* __restrict__ kfc2w, const float* __restrict__ kfc2b,
    const float* __restrict__ kfc3w, const float* __restrict__ kfc3b,
    const float* __restrict__ efc1w, const float* __restrict__ efc1b,
    const float* __restrict__ efc2w, const float* __restrict__ efc2b,
    float* __restrict__ out)
{
    int wave = threadIdx.x >> 6, lane = threadIdx.x & 63;
    int bid = blockIdx.x;
    int kind, r0, sn, baseC, baseD;
    const u16 *wc, *wd;
    const void *A;
    const float *w2, *b2, *w3, *b3;
    float* outp;
    if (bid < KBLK){
        kind=0; r0=bid*64; sn=N_K; baseC=PB1; baseD=PB2;
        wc=Wf; wd=Wf+16384; A=knA; w2=kfc2w; b2=kfc2b; w3=kfc3w; b3=kfc3b; outp=out;
    } else if (bid < KBLK+EBLK){
        kind=0; r0=(bid-KBLK)*64; sn=N_E; baseC=PB3; baseD=PB5;
        wc=Wf+2*16384; wd=Wf+4*16384; A=exerA; w2=efc1w; b2=efc1b; w3=efc2w; b3=efc2b;
        outp=out + (size_t)N_K*128;
    } else {
        kind=1; r0=(bid-KBLK-EBLK)*64; sn=N_U; baseC=PB4; baseD=PB4;
        wc=Wf+3*16384; wd=nullptr; A=stuA; w2=nullptr; b2=nullptr; w3=nullptr; b3=nullptr;
        outp=out + (size_t)(N_K+N_E)*128;
    }
    int lrow = r0 + wave*16;
    if (lrow >= sn) return;           // sn % 16 == 0 -> whole-wave validity
    int colb = lane & 15;
    int rlo  = (lane>>4)*4;
    const float* Af = (const float*)A;
    const u16*   Ab = (const u16*)A;

    // --- C gemm ---
    f32x4 accC[8];
    #pragma unroll
    for (int ct = 0; ct < 8; ++ct) accC[ct] = (f32x4){0.f,0.f,0.f,0.f};
    {
        const u16* ap = agg + (size_t)(baseC + lrow + colb)*128 + ((lane>>4)*8);
        bf16x8 af[4];
        #pragma unroll
        for (int ks = 0; ks < 4; ++ks) af[ks] = *(const bf16x8*)(ap + ks*32);
        #pragma unroll
        for (int ks = 0; ks < 4; ++ks)
            #pragma unroll
            for (int ct = 0; ct < 8; ++ct){
                bf16x8 b = *(const bf16x8*)(wc + ((size_t)((ct*4+ks)*64 + lane))*8);
                accC[ct] = __builtin_amdgcn_mfma_f32_16x16x32_bf16(af[ks], b, accC[ct], 0, 0, 0);
            }
    }

    if (kind == 1){
        #pragma unroll
        for (int ct = 0; ct < 8; ++ct)
            #pragma unroll
            for (int j = 0; j < 4; ++j){
                size_t idx = (size_t)(lrow + rlo + j)*128 + ct*16 + colb;
                float av = BF ? bf2f(Ab[idx]) : Af[idx];
                outp[idx] = accC[ct][j] + av;
            }
        return;
    }

    // --- D gemm ---
    f32x4 accD[8];
    #pragma unroll
    for (int ct = 0; ct < 8; ++ct) accD[ct] = (f32x4){0.f,0.f,0.f,0.f};
    {
        const u16* ap = agg + (size_t)(baseD + lrow + colb)*128 + ((lane>>4)*8);
        bf16x8 af[4];
        #pragma unroll
        for (int ks = 0; ks < 4; ++ks) af[ks] = *(const bf16x8*)(ap + ks*32);
        #pragma unroll
        for (int ks = 0; ks < 4; ++ks)
            #pragma unroll
            for (int ct = 0; ct < 8; ++ct){
                bf16x8 b = *(const bf16x8*)(wd + ((size_t)((ct*4+ks)*64 + lane))*8);
                accD[ct] = __builtin_amdgcn_mfma_f32_16x16x32_bf16(af[ks], b, accD[ct], 0, 0, 0);
            }
    }

    // --- gating epilogue ---
    float w2l[8], w2h[8], w3l[8], w3h[8];
    #pragma unroll
    for (int ct = 0; ct < 8; ++ct){
        int c = ct*16 + colb;
        w2l[ct] = w2[c]; w2h[ct] = w2[128+c];
        w3l[ct] = w3[c]; w3h[ct] = w3[128+c];
    }
    float aA[8][4];
    #pragma unroll
    for (int ct = 0; ct < 8; ++ct)
        #pragma unroll
        for (int j = 0; j < 4; ++j){
            size_t idx = (size_t)(lrow + rlo + j)*128 + ct*16 + colb;
            aA[ct][j] = BF ? bf2f(Ab[idx]) : Af[idx];
        }
    float s2p[4] = {0.f,0.f,0.f,0.f}, s3p[4] = {0.f,0.f,0.f,0.f};
    #pragma unroll
    for (int ct = 0; ct < 8; ++ct)
        #pragma unroll
        for (int j = 0; j < 4; ++j){
            s2p[j] = fmaf(aA[ct][j], w2l[ct], fmaf(accC[ct][j], w2h[ct], s2p[j]));
            s3p[j] = fmaf(aA[ct][j], w3l[ct], fmaf(accD[ct][j], w3h[ct], s3p[j]));
        }
    #pragma unroll
    for (int m = 8; m; m >>= 1)
        #pragma unroll
        for (int j = 0; j < 4; ++j){
            s2p[j] += __shfl_xor(s2p[j], m);
            s3p[j] += __shfl_xor(s3p[j], m);
        }
    float bb2 = b2[0], bb3 = b3[0];
    #pragma unroll
    for (int j = 0; j < 4; ++j){
        float s2 = s2p[j] + bb2, s3 = s3p[j] + bb3;
        float mx = fmaxf(s2, s3);
        float e2 = __expf(s2 - mx), e3 = __expf(s3 - mx);
        float inv = 1.f/(e2 + e3);
        float p2 = e2*inv, p3 = e3*inv;
        #pragma unroll
        for (int ct = 0; ct < 8; ++ct){
            size_t idx = (size_t)(lrow + rlo + j)*128 + ct*16 + colb;
            outp[idx] = aA[ct][j] + p2*accC[ct][j] + p3*accD[ct][j];
        }
    }
}

extern "C" void kernel_launch(void* const* d_in, const int* in_sizes, int n_in,
                              void* d_out, int out_size, void* d_ws, size_t ws_size,
                              hipStream_t stream)
{
    (void)in_sizes; (void)n_in; (void)out_size;
    const float* kn   = (const float*)d_in[0];
    const float* exer = (const float*)d_in[1];
    const float* stu  = (const float*)d_in[2];
    const int* und_src = (const int*)d_in[3];
    const int* und_dst = (const int*)d_in[4];
    const int* ek_src  = (const int*)d_in[5];
    const int* ek_dst  = (const int*)d_in[6];
    const int* eu_src  = (const int*)d_in[7];
    const int* eu_dst  = (const int*)d_in[8];
    const float* W_und = (const float*)d_in[9];  const float* a_und = (const float*)d_in[10];
    const float* W_ek  = (const float*)d_in[11]; const float* a_ek  = (const float*)d_in[12];
    const float* W_ke  = (const float*)d_in[13]; const float* a_ke  = (const float*)d_in[14];
    const float* W_eu  = (const float*)d_in[15]; const float* a_eu  = (const float*)d_in[16];
    const float* W_ue  = (const float*)d_in[17]; const float* a_ue  = (const float*)d_in[18];
    const float* kfc2w = (const float*)d_in[19]; const float* kfc2b = (const float*)d_in[20];
    const float* kfc3w = (const float*)d_in[21]; const float* kfc3b = (const float*)d_in[22];
    const float* efc1w = (const float*)d_in[23]; const float* efc1b = (const float*)d_in[24];
    const float* efc2w = (const float*)d_in[25]; const float* efc2b = (const float*)d_in[26];

    char* base = (char*)d_ws;
    size_t off_b = 0;
    auto alloc = [&](size_t bytes)->char*{
        char* p = base + off_b;
        off_b += (bytes + 255) & ~(size_t)255;
        return p;
    };
    float* vecs = (float*)alloc(1280*4);
    u16*   Wf   = (u16*)  alloc(5*16384*2);
    float* el1 = (float*)alloc(N_K*4);
    float* el2 = (float*)alloc(N_E*4);
    float* el3 = (float*)alloc(N_K*4);
    float* el4 = (float*)alloc(N_E*4);
    float* el5 = (float*)alloc(N_U*4);
    float* erc = (float*)alloc((size_t)N_TOT*4);     // concat er, indexed by key
    int* cnt  = (int*)alloc((size_t)N_TOT*4);
    int* offA = (int*)alloc((size_t)N_TOT*4);
    int* cur  = (int*)alloc((size_t)N_TOT*4);
    int* bsum = (int*)alloc(1024*4);
    int2* sorted2 = (int2*)alloc((size_t)E_TOT*8);   // {src, ev}
    u16* agg  = (u16*)alloc((size_t)PTOT*128*2);
    u16* knb   = (u16*)alloc((size_t)N_K*128*2);
    u16* exerb = (u16*)alloc((size_t)N_E*128*2);
    u16* stub  = (u16*)alloc((size_t)N_U*128*2);
    size_t need_bf = off_b;
    bool useBF = (ws_size >= need_bf);
    float* out = (float*)d_out;

    const int NBLK = (N_TOT + 255)/256;     // 938 (<=1024 for scan2)

    hipMemsetAsync(cnt, 0, (size_t)N_TOT*4, stream);

    prep_vecs<<<10,128,0,stream>>>(W_und,W_ek,W_ke,W_eu,W_ue, a_und,a_ek,a_ke,a_eu,a_ue, vecs);
    fragify<<<5,256,0,stream>>>(W_und,W_ek,W_ke,W_eu,W_ue, Wf);

    // fused conv(f32->bf16) + el/er dots; wl_g = vecs+g*128, wr_g = vecs+(5+g)*128
    // g: 0=und 1=ek 2=ke 3=eu 4=ue.  er outputs go straight into erc at key bases.
    if (useBF){
        conv_dot<4,1><<<(N_K+3)/4,256,0,stream>>>(kn,   knb,   vecs+0,    vecs+640, vecs+768,  vecs+256,  el1, erc+KB1, erc+KB2, el3, N_K);
        conv_dot<4,1><<<(N_E+3)/4,256,0,stream>>>(exer, exerb, vecs+128,  vecs+896, vecs+384,  vecs+1152, el2, erc+KB3, el4, erc+KB5, N_E);
        conv_dot<2,1><<<(N_U+3)/4,256,0,stream>>>(stu,  stub,  vecs+1024, vecs+512, nullptr, nullptr, erc+KB4, el5, nullptr, nullptr, N_U);
    } else {
        conv_dot<4,0><<<(N_K+3)/4,256,0,stream>>>(kn,   nullptr, vecs+0,    vecs+640, vecs+768,  vecs+256,  el1, erc+KB1, erc+KB2, el3, N_K);
        conv_dot<4,0><<<(N_E+3)/4,256,0,stream>>>(exer, nullptr, vecs+128,  vecs+896, vecs+384,  vecs+1152, el2, erc+KB3, el4, erc+KB5, N_E);
        conv_dot<2,0><<<(N_U+3)/4,256,0,stream>>>(stu,  nullptr, vecs+1024, vecs+512, nullptr, nullptr, erc+KB4, el5, nullptr, nullptr, N_U);
    }

    count_all<<<(E_TOT+255)/256,256,0,stream>>>(und_dst, ek_src, ek_dst, eu_src, eu_dst, cnt);
    scan1<<<NBLK,256,0,stream>>>(cnt, offA, bsum, N_TOT);
    scan2<<<1,1024,0,stream>>>(bsum, NBLK);
    scan3<<<NBLK,256,0,stream>>>(offA, cur, bsum, N_TOT);

    // range-partitioned fill (4 passes): L2/LLC-hot write slices + ev precompute
    {
        const int KR = (N_TOT + 3) / 4;   // 60000
        for (int p = 0; p < 4; ++p){
            fill_ev<<<(E_TOT+255)/256,256,0,stream>>>(und_src, und_dst, ek_src, ek_dst,
                                                      eu_src, eu_dst,
                                                      el1, el2, el3, el4, el5, erc,
                                                      cur, sorted2,
                                                      p*KR, (p == 3) ? N_TOT : (p+1)*KR);
        }
    }

    if (useBF){
        aggregate_all<1><<<(PTOT+3)/4,256,0,stream>>>(cnt, offA, sorted2, knb, exerb, stub, agg);
        gemm_epi<1><<<KBLK+EBLK+SBLK,256,0,stream>>>(agg, Wf, knb, exerb, stub,
                                                     kfc2w,kfc2b,kfc3w,kfc3b,
                                                     efc1w,efc1b,efc2w,efc2b, out);
    } else {
        aggregate_all<0><<<(PTOT+3)/4,256,0,stream>>>(cnt, offA, sorted2, kn, exer, stu, agg);
        gemm_epi<0><<<KBLK+EBLK+SBLK,256,0,stream>>>(agg, Wf, kn, exer, stu,
                                                     kfc2w,kfc2b,kfc3w,kfc3b,
                                                     efc1w,efc1b,efc2w,efc2b, out);
    }
}

// Round 8
// 308.667 us; speedup vs baseline: 1.4128x; 1.4128x over previous
//
#include <hip/hip_runtime.h>

#define N_K 20000
#define N_E 50000
#define N_U 100000
#define E_TOT 2200000
#define N_TOT 240000
// padded (64-aligned) agg-row segment bases: GAT1 kn | GAT2 kn | GAT3 exer | GAT4 stu | GAT5 exer
#define PB1 0
#define PB2 20032
#define PB3 40064
#define PB4 90112
#define PB5 190144
#define PTOT 240192
// key-space (concat dst) bases
#define KB1 0
#define KB2 20000
#define KB3 40000
#define KB4 90000
#define KB5 190000
// bucket sort geometry
#define NBKT 726
#define EPB 8192
#define NBLKA 269          // ceil(E_TOT / EPB)
#define APAD 272

typedef unsigned short u16;
typedef unsigned int u32;
typedef __bf16 bf16x8 __attribute__((ext_vector_type(8)));
typedef float f32x4 __attribute__((ext_vector_type(4)));

__device__ __forceinline__ float bf2f(u16 v){
    union { u32 u; float f; } x; x.u = ((u32)v) << 16; return x.f;
}
__device__ __forceinline__ u16 f2bf(float f){
    union { float f; u32 u; } x; x.f = f;
    u32 r = x.u + 0x7FFFu + ((x.u >> 16) & 1u);
    return (u16)(r >> 16);
}
__device__ __forceinline__ float leaky_exp(float x){
    x = x >= 0.f ? x : 0.01f*x;
    return __expf(x);
}

// bucket mapping: per-range shifts chosen so each bucket has <=512 keys, ~2.5-4k edges
__device__ __forceinline__ int bucket_of(int key){
    if (key < 20000)  return key >> 8;                     // 0..78
    if (key < 40000)  return 79  + ((key - 20000) >> 7);   // 79..235
    if (key < 90000)  return 236 + ((key - 40000) >> 9);   // 236..333
    if (key < 190000) return 334 + ((key - 90000) >> 9);   // 334..529
    return 530 + ((key - 190000) >> 8);                    // 530..725
}
__device__ __forceinline__ void bucket_info(int b, int& kb, int& w, int& r){
    if (b < 79){       r=0; kb = b << 8;                 w = min(256, 20000  - kb); }
    else if (b < 236){ r=1; kb = 20000 + ((b-79)  << 7); w = min(128, 40000  - kb); }
    else if (b < 334){ r=2; kb = 40000 + ((b-236) << 9); w = min(512, 90000  - kb); }
    else if (b < 530){ r=3; kb = 90000 + ((b-334) << 9); w = min(512, 190000 - kb); }
    else {             r=4; kb = 190000 + ((b-530) << 8); w = min(256, 240000 - kb); }
}
__device__ __forceinline__ int edge_key(int e,
    const int* ud, const int* es, const int* ed, const int* vs, const int* vd){
    if (e < 200000)  return ud[e];
    if (e < 600000)  return 20000  + ed[e-200000];
    if (e < 1000000) return 40000  + es[e-600000];
    if (e < 1600000) return 90000  + vd[e-1000000];
    return 190000 + vs[e-1600000];
}
__device__ __forceinline__ int edge_src(int e,
    const int* us, const int* es, const int* ed, const int* vs, const int* vd){
    if (e < 200000)  return us[e];
    if (e < 600000)  return es[e-200000];
    if (e < 1000000) return ed[e-600000];
    if (e < 1600000) return vs[e-1000000];
    return vd[e-1600000];
}

// ------------------------------------------------- fused weight prep (vecs + MFMA frags)
// blocks 0..319: vecs (wave per output, 1280 outputs). blocks 320..359: fragify.
__global__ __launch_bounds__(256) void prep_w(
    const float* W0, const float* W1, const float* W2, const float* W3, const float* W4,
    const float* a0, const float* a1, const float* a2, const float* a3, const float* a4,
    float* __restrict__ vecs, u16* __restrict__ Wf)
{
    int bid = blockIdx.x;
    if (bid < 320){
        int o = bid*4 + (threadIdx.x >> 6);
        int lane = threadIdx.x & 63;
        int which = o / 640, rem = o - which*640, g = rem >> 7, k = rem & 127;
        const float* W = g==0?W0:g==1?W1:g==2?W2:g==3?W3:W4;
        const float* a = g==0?a0:g==1?a1:g==2?a2:g==3?a3:a4;
        const float* av = a + which*128;
        int c = lane*2;
        float s = W[k*128 + c]*av[c] + W[k*128 + c + 1]*av[c+1];
        #pragma unroll
        for (int m = 32; m; m >>= 1) s += __shfl_xor(s, m);
        if (lane == 0) vecs[(which*5 + g)*128 + k] = s;
    } else {
        int t = (bid - 320)*256 + threadIdx.x;   // 0..10239
        int g = t / 2048, i = t - g*2048;
        const float* W = g==0?W0:g==1?W1:g==2?W2:g==3?W3:W4;
        int lane = i & 63, tt = i >> 6, ks = tt & 3, ct = tt >> 2;
        int kbase = ks*32 + (lane>>4)*8;
        int c = ct*16 + (lane&15);
        #pragma unroll
        for (int j = 0; j < 8; ++j)
            Wf[g*16384 + i*8 + j] = f2bf(W[(kbase+j)*128 + c]);
    }
}

// ------------------------------------------------- fused conv(f32->bf16) + row dots
template<int ND, int WBF>
__global__ __launch_bounds__(256) void conv_dot(const float* __restrict__ h, u16* __restrict__ hb,
    const float* __restrict__ v0, const float* __restrict__ v1,
    const float* __restrict__ v2, const float* __restrict__ v3,
    float* __restrict__ o0, float* __restrict__ o1,
    float* __restrict__ o2, float* __restrict__ o3, int nrows)
{
    int w = (int)((blockIdx.x*(u32)blockDim.x + threadIdx.x) >> 6);
    int lane = threadIdx.x & 63;
    if (w >= nrows) return;
    float2 hv = *(const float2*)(h + (size_t)w*128 + lane*2);
    if (WBF)
        *(u32*)(hb + (size_t)w*128 + lane*2) = (u32)f2bf(hv.x) | ((u32)f2bf(hv.y) << 16);
    int c = lane*2;
    float d0 = hv.x*v0[c] + hv.y*v0[c+1];
    float d1 = hv.x*v1[c] + hv.y*v1[c+1];
    float d2 = 0.f, d3 = 0.f;
    if (ND == 4){
        d2 = hv.x*v2[c] + hv.y*v2[c+1];
        d3 = hv.x*v3[c] + hv.y*v3[c+1];
    }
    #pragma unroll
    for (int o = 32; o; o >>= 1){
        d0 += __shfl_xor(d0, o); d1 += __shfl_xor(d1, o);
        if (ND == 4){ d2 += __shfl_xor(d2, o); d3 += __shfl_xor(d3, o); }
    }
    if (lane == 0){
        o0[w] = d0; o1[w] = d1;
        if (ND == 4){ o2[w] = d2; o3[w] = d3; }
    }
}

// ------------------------------------------------- atomic-free CSR build
// A: per-block LDS bucket histogram -> hist[bucket][block]
__global__ __launch_bounds__(256) void bkt_hist(
    const int* __restrict__ ud, const int* __restrict__ es, const int* __restrict__ ed,
    const int* __restrict__ vs, const int* __restrict__ vd, int* __restrict__ hist)
{
    __shared__ int h[NBKT];
    for (int i = threadIdx.x; i < NBKT; i += 256) h[i] = 0;
    __syncthreads();
    int base = blockIdx.x * EPB;
    #pragma unroll 4
    for (int it = 0; it < EPB/256; ++it){
        int e = base + it*256 + threadIdx.x;
        if (e < E_TOT){
            int key = edge_key(e, ud, es, ed, vs, vd);
            atomicAdd(&h[bucket_of(key)], 1);
        }
    }
    __syncthreads();
    for (int i = threadIdx.x; i < NBKT; i += 256)
        hist[i*APAD + blockIdx.x] = h[i];
}

// B1: per bucket, exclusive scan over blocks; totals out
__global__ __launch_bounds__(512) void bkt_scan1(int* __restrict__ hist, int* __restrict__ btot)
{
    __shared__ int sm[512];
    int t = threadIdx.x;
    int v = (t < NBLKA) ? hist[blockIdx.x*APAD + t] : 0;
    sm[t] = v; __syncthreads();
    #pragma unroll
    for (int d = 1; d < 512; d <<= 1){
        int x = (t >= d) ? sm[t-d] : 0;
        __syncthreads();
        sm[t] += x;
        __syncthreads();
    }
    if (t < NBLKA) hist[blockIdx.x*APAD + t] = sm[t] - v;
    if (t == 511) btot[blockIdx.x] = sm[511];
}

// B2: exclusive scan over bucket totals -> bucket bases
__global__ __launch_bounds__(1024) void bkt_scan2(const int* __restrict__ btot, int* __restrict__ bbase)
{
    __shared__ int sm[1024];
    int t = threadIdx.x;
    int v = (t < NBKT) ? btot[t] : 0;
    sm[t] = v; __syncthreads();
    #pragma unroll
    for (int d = 1; d < 1024; d <<= 1){
        int x = (t >= d) ? sm[t-d] : 0;
        __syncthreads();
        sm[t] += x;
        __syncthreads();
    }
    if (t < NBKT) bbase[t] = sm[t] - v;
}

// C: scatter (src,key) records into bucket-grouped array; LDS cursors only
__global__ __launch_bounds__(256) void bkt_scatter(
    const int* __restrict__ us, const int* __restrict__ ud,
    const int* __restrict__ es, const int* __restrict__ ed,
    const int* __restrict__ vs, const int* __restrict__ vd,
    const int* __restrict__ hist, const int* __restrict__ bbase,
    uint2* __restrict__ rec)
{
    __shared__ int cur[NBKT];
    for (int i = threadIdx.x; i < NBKT; i += 256)
        cur[i] = bbase[i] + hist[i*APAD + blockIdx.x];
    __syncthreads();
    int base = blockIdx.x * EPB;
    #pragma unroll 4
    for (int it = 0; it < EPB/256; ++it){
        int e = base + it*256 + threadIdx.x;
        if (e < E_TOT){
            int key = edge_key(e, ud, es, ed, vs, vd);
            int src = edge_src(e, us, es, ed, vs, vd);
            int pos = atomicAdd(&cur[bucket_of(key)], 1);
            rec[pos] = make_uint2((u32)src, (u32)key);
        }
    }
}

// Dpre: per-bucket exact key histogram -> cnt (replaces global-atomic count)
__global__ __launch_bounds__(256) void bkt_cnt(const uint2* __restrict__ rec,
    const int* __restrict__ bbase, const int* __restrict__ btot, int* __restrict__ cnt)
{
    __shared__ int h[512];
    int b = blockIdx.x;
    int kb, w, r;
    bucket_info(b, kb, w, r);
    for (int i = threadIdx.x; i < 512; i += 256) h[i] = 0;
    __syncthreads();
    int start = bbase[b], n = btot[b];
    for (int i = threadIdx.x; i < n; i += 256)
        atomicAdd(&h[(int)rec[start+i].y - kb], 1);
    __syncthreads();
    for (int i = threadIdx.x; i < w; i += 256)
        cnt[kb + i] = h[i];
}

// block-level exclusive scan over cnt -> offA (Hillis-Steele in LDS)
__global__ void scan1(const int* __restrict__ cnt, int* __restrict__ off, int* __restrict__ bsum, int n){
    __shared__ int sm[256];
    int t = threadIdx.x;
    int i = blockIdx.x*256 + t;
    int v = (i < n) ? cnt[i] : 0;
    sm[t] = v; __syncthreads();
    #pragma unroll
    for (int d = 1; d < 256; d <<= 1){
        int x = (t >= d) ? sm[t-d] : 0;
        __syncthreads();
        sm[t] += x;
        __syncthreads();
    }
    if (i < n) off[i] = sm[t] - v;
    if (t == 255) bsum[blockIdx.x] = sm[255];
}
__global__ void scan2(int* __restrict__ bsum, int nb){
    __shared__ int sm[1024];
    int t = threadIdx.x;
    int v = (t < nb) ? bsum[t] : 0;
    sm[t] = v; __syncthreads();
    #pragma unroll
    for (int d = 1; d < 1024; d <<= 1){
        int x = (t >= d) ? sm[t-d] : 0;
        __syncthreads();
        sm[t] += x;
        __syncthreads();
    }
    if (t < nb) bsum[t] = sm[t] - v;
}
__global__ void scan3(int* __restrict__ off, const int* __restrict__ bsum, int n){
    int i = blockIdx.x*256 + threadIdx.x;
    if (i < n) off[i] += bsum[blockIdx.x];
}

// D: per-bucket final placement into sorted2 (+ev); LDS cursors seeded with offA
__global__ __launch_bounds__(256) void bkt_fill(const uint2* __restrict__ rec,
    const int* __restrict__ bbase, const int* __restrict__ btot,
    const int* __restrict__ offA, const float* __restrict__ erc,
    const float* __restrict__ el1, const float* __restrict__ el2,
    const float* __restrict__ el3, const float* __restrict__ el4,
    const float* __restrict__ el5, int2* __restrict__ sorted2)
{
    __shared__ int curk[512];
    __shared__ float ercs[512];
    int b = blockIdx.x;
    int kb, w, r;
    bucket_info(b, kb, w, r);
    for (int i = threadIdx.x; i < w; i += 256){
        curk[i] = offA[kb + i];
        ercs[i] = erc[kb + i];
    }
    __syncthreads();
    const float* el = r==0?el1 : r==1?el2 : r==2?el3 : r==3?el4 : el5;
    int start = bbase[b], n = btot[b];
    for (int i = threadIdx.x; i < n; i += 256){
        uint2 rc = rec[start + i];
        int local = (int)rc.y - kb;
        float ev = leaky_exp(el[rc.x] + ercs[local]);
        int pos = atomicAdd(&curk[local], 1);
        sorted2[pos] = make_int2((int)rc.x, __float_as_int(ev));
    }
}

// ------------------------------------------------- fused GAT aggregation (r6 layout)
template<int BF>
__global__ __launch_bounds__(256) void aggregate_all(
    const int* __restrict__ cnt, const int* __restrict__ off, const int2* __restrict__ sorted2,
    const void* __restrict__ hk, const void* __restrict__ he, const void* __restrict__ hs,
    u16* __restrict__ agg)
{
    int row = (int)((blockIdx.x*(u32)blockDim.x + threadIdx.x) >> 6);
    int lane = threadIdx.x & 63;
    if (row >= PTOT) return;
    int local, nb, sn;
    const void* h;
    if (row < PB2){ local=row;      nb=KB1; sn=N_K; h=hk; }
    else if (row < PB3){ local=row-PB2; nb=KB2; sn=N_K; h=he; }
    else if (row < PB4){ local=row-PB3; nb=KB3; sn=N_E; h=hk; }
    else if (row < PB5){ local=row-PB4; nb=KB4; sn=N_U; h=he; }
    else {              local=row-PB5; nb=KB5; sn=N_E; h=hs; }
    if (local >= sn) return;   // 64-pad tail
    int ci = nb + local;
    int deg = cnt[ci], start = off[ci];
    float a0 = 0.f, a1 = 0.f, ssum = 0.f;
    const u32* hb32 = (const u32*)h;
    const float2* hf2 = (const float2*)h;
    int i = 0;
    for (; i + 8 <= deg; i += 8){
        int2 w[8];
        #pragma unroll
        for (int j = 0; j < 8; ++j) w[j] = sorted2[start+i+j];
        if (BF){
            u32 hv[8];
            #pragma unroll
            for (int j = 0; j < 8; ++j) hv[j] = hb32[(size_t)w[j].x*64 + lane];
            #pragma unroll
            for (int j = 0; j < 8; ++j){
                float ev = __int_as_float(w[j].y);
                a0 = fmaf(ev, bf2f((u16)hv[j]), a0);
                a1 = fmaf(ev, bf2f((u16)(hv[j]>>16)), a1);
                ssum += ev;
            }
        } else {
            float2 hv[8];
            #pragma unroll
            for (int j = 0; j < 8; ++j) hv[j] = hf2[(size_t)w[j].x*64 + lane];
            #pragma unroll
            for (int j = 0; j < 8; ++j){
                float ev = __int_as_float(w[j].y);
                a0 = fmaf(ev, hv[j].x, a0);
                a1 = fmaf(ev, hv[j].y, a1);
                ssum += ev;
            }
        }
    }
    for (; i + 4 <= deg; i += 4){
        int2 w[4];
        #pragma unroll
        for (int j = 0; j < 4; ++j) w[j] = sorted2[start+i+j];
        if (BF){
            u32 hv[4];
            #pragma unroll
            for (int j = 0; j < 4; ++j) hv[j] = hb32[(size_t)w[j].x*64 + lane];
            #pragma unroll
            for (int j = 0; j < 4; ++j){
                float ev = __int_as_float(w[j].y);
                a0 = fmaf(ev, bf2f((u16)hv[j]), a0);
                a1 = fmaf(ev, bf2f((u16)(hv[j]>>16)), a1);
                ssum += ev;
            }
        } else {
            float2 hv[4];
            #pragma unroll
            for (int j = 0; j < 4; ++j) hv[j] = hf2[(size_t)w[j].x*64 + lane];
            #pragma unroll
            for (int j = 0; j < 4; ++j){
                float ev = __int_as_float(w[j].y);
                a0 = fmaf(ev, hv[j].x, a0);
                a1 = fmaf(ev, hv[j].y, a1);
                ssum += ev;
            }
        }
    }
    for (; i < deg; ++i){
        int2 w = sorted2[start + i];
        float ev = __int_as_float(w.y);
        float x0, x1;
        if (BF){
            u32 hv = hb32[(size_t)w.x*64 + lane];
            x0 = bf2f((u16)hv); x1 = bf2f((u16)(hv>>16));
        } else {
            float2 hv = hf2[(size_t)w.x*64 + lane];
            x0 = hv.x; x1 = hv.y;
        }
        a0 = fmaf(ev, x0, a0);
        a1 = fmaf(ev, x1, a1);
        ssum += ev;
    }
    float inv = (ssum > 0.f) ? 1.f/ssum : 0.f;
    *(u32*)(agg + (size_t)row*128 + lane*2) = (u32)f2bf(a0*inv) | ((u32)f2bf(a1*inv) << 16);
}

// ------------------------------------------------- fused dual-GEMM + gating epilogue
#define KBLK 313
#define EBLK 782
#define SBLK 1563
template<int BF>
__global__ __launch_bounds__(256) void gemm_epi(const u16* __restrict__ agg, const u16* __restrict__ Wf,
    const void* __restrict__ knA, const void* __restrict__ exerA, const void* __restrict__ stuA,
    const float* __restrict__ kfc2w, const float* __restrict__ kfc2b,
    const float* __restrict__ kfc3w, const float* __restrict__ kfc3b,
    const float* __restrict__ efc1w, const float* __restrict__ efc1b,
    const float* __restrict__ efc2w, const float* __restrict__ efc2b,
    float* __restrict__ out)
{
    int wave = threadIdx.x >> 6, lane = threadIdx.x & 63;
    int bid = blockIdx.x;
    int kind, r0, sn, baseC, baseD;
    const u16 *wc, *wd;
    const void *A;
    const float *w2, *b2, *w3, *b3;
    float* outp;
    if (bid < KBLK){
        kind=0; r0=bid*64; sn=N_K; baseC=PB1; baseD=PB2;
        wc=Wf; wd=Wf+16384; A=knA; w2=kfc2w; b2=kfc2b; w3=kfc3w; b3=kfc3b; outp=out;
    } else if (bid < KBLK+EBLK){
        kind=0; r0=(bid-KBLK)*64; sn=N_E; baseC=PB3; baseD=PB5;
        wc=Wf+2*16384; wd=Wf+4*16384; A=exerA; w2=efc1w; b2=efc1b; w3=efc2w; b3=efc2b;
        outp=out + (size_t)N_K*128;
    } else {
        kind=1; r0=(bid-KBLK-EBLK)*64; sn=N_U; baseC=PB4; baseD=PB4;
        wc=Wf+3*16384; wd=nullptr; A=stuA; w2=nullptr; b2=nullptr; w3=nullptr; b3=nullptr;
        outp=out + (size_t)(N_K+N_E)*128;
    }
    int lrow = r0 + wave*16;
    if (lrow >= sn) return;
    int colb = lane & 15;
    int rlo  = (lane>>4)*4;
    const float* Af = (const float*)A;
    const u16*   Ab = (const u16*)A;

    f32x4 accC[8];
    #pragma unroll
    for (int ct = 0; ct < 8; ++ct) accC[ct] = (f32x4){0.f,0.f,0.f,0.f};
    {
        const u16* ap = agg + (size_t)(baseC + lrow + colb)*128 + ((lane>>4)*8);
        bf16x8 af[4];
        #pragma unroll
        for (int ks = 0; ks < 4; ++ks) af[ks] = *(const bf16x8*)(ap + ks*32);
        #pragma unroll
        for (int ks = 0; ks < 4; ++ks)
            #pragma unroll
            for (int ct = 0; ct < 8; ++ct){
                bf16x8 b = *(const bf16x8*)(wc + ((size_t)((ct*4+ks)*64 + lane))*8);
                accC[ct] = __builtin_amdgcn_mfma_f32_16x16x32_bf16(af[ks], b, accC[ct], 0, 0, 0);
            }
    }

    if (kind == 1){
        #pragma unroll
        for (int ct = 0; ct < 8; ++ct)
            #pragma unroll
            for (int j = 0; j < 4; ++j){
                size_t idx = (size_t)(lrow + rlo + j)*128 + ct*16 + colb;
                float av = BF ? bf2f(Ab[idx]) : Af[idx];
                outp[idx] = accC[ct][j] + av;
            }
        return;
    }

    f32x4 accD[8];
    #pragma unroll
    for (int ct = 0; ct < 8; ++ct) accD[ct] = (f32x4){0.f,0.f,0.f,0.f};
    {
        const u16* ap = agg + (size_t)(baseD + lrow + colb)*128 + ((lane>>4)*8);
        bf16x8 af[4];
        #pragma unroll
        for (int ks = 0; ks < 4; ++ks) af[ks] = *(const bf16x8*)(ap + ks*32);
        #pragma unroll
        for (int ks = 0; ks < 4; ++ks)
            #pragma unroll
            for (int ct = 0; ct < 8; ++ct){
                bf16x8 b = *(const bf16x8*)(wd + ((size_t)((ct*4+ks)*64 + lane))*8);
                accD[ct] = __builtin_amdgcn_mfma_f32_16x16x32_bf16(af[ks], b, accD[ct], 0, 0, 0);
            }
    }

    float w2l[8], w2h[8], w3l[8], w3h[8];
    #pragma unroll
    for (int ct = 0; ct < 8; ++ct){
        int c = ct*16 + colb;
        w2l[ct] = w2[c]; w2h[ct] = w2[128+c];
        w3l[ct] = w3[c]; w3h[ct] = w3[128+c];
    }
    float aA[8][4];
    #pragma unroll
    for (int ct = 0; ct < 8; ++ct)
        #pragma unroll
        for (int j = 0; j < 4; ++j){
            size_t idx = (size_t)(lrow + rlo + j)*128 + ct*16 + colb;
            aA[ct][j] = BF ? bf2f(Ab[idx]) : Af[idx];
        }
    float s2p[4] = {0.f,0.f,0.f,0.f}, s3p[4] = {0.f,0.f,0.f,0.f};
    #pragma unroll
    for (int ct = 0; ct < 8; ++ct)
        #pragma unroll
        for (int j = 0; j < 4; ++j){
            s2p[j] = fmaf(aA[ct][j], w2l[ct], fmaf(accC[ct][j], w2h[ct], s2p[j]));
            s3p[j] = fmaf(aA[ct][j], w3l[ct], fmaf(accD[ct][j], w3h[ct], s3p[j]));
        }
    #pragma unroll
    for (int m = 8; m; m >>= 1)
        #pragma unroll
        for (int j = 0; j < 4; ++j){
            s2p[j] += __shfl_xor(s2p[j], m);
            s3p[j] += __shfl_xor(s3p[j], m);
        }
    float bb2 = b2[0], bb3 = b3[0];
    #pragma unroll
    for (int j = 0; j < 4; ++j){
        float s2 = s2p[j] + bb2, s3 = s3p[j] + bb3;
        float mx = fmaxf(s2, s3);
        float e2 = __expf(s2 - mx), e3 = __expf(s3 - mx);
        float inv = 1.f/(e2 + e3);
        float p2 = e2*inv, p3 = e3*inv;
        #pragma unroll
        for (int ct = 0; ct < 8; ++ct){
            size_t idx = (size_t)(lrow + rlo + j)*128 + ct*16 + colb;
            outp[idx] = aA[ct][j] + p2*accC[ct][j] + p3*accD[ct][j];
        }
    }
}

extern "C" void kernel_launch(void* const* d_in, const int* in_sizes, int n_in,
                              void* d_out, int out_size, void* d_ws, size_t ws_size,
                              hipStream_t stream)
{
    (void)in_sizes; (void)n_in; (void)out_size;
    const float* kn   = (const float*)d_in[0];
    const float* exer = (const float*)d_in[1];
    const float* stu  = (const float*)d_in[2];
    const int* und_src = (const int*)d_in[3];
    const int* und_dst = (const int*)d_in[4];
    const int* ek_src  = (const int*)d_in[5];
    const int* ek_dst  = (const int*)d_in[6];
    const int* eu_src  = (const int*)d_in[7];
    const int* eu_dst  = (const int*)d_in[8];
    const float* W_und = (const float*)d_in[9];  const float* a_und = (const float*)d_in[10];
    const float* W_ek  = (const float*)d_in[11]; const float* a_ek  = (const float*)d_in[12];
    const float* W_ke  = (const float*)d_in[13]; const float* a_ke  = (const float*)d_in[14];
    const float* W_eu  = (const float*)d_in[15]; const float* a_eu  = (const float*)d_in[16];
    const float* W_ue  = (const float*)d_in[17]; const float* a_ue  = (const float*)d_in[18];
    const float* kfc2w = (const float*)d_in[19]; const float* kfc2b = (const float*)d_in[20];
    const float* kfc3w = (const float*)d_in[21]; const float* kfc3b = (const float*)d_in[22];
    const float* efc1w = (const float*)d_in[23]; const float* efc1b = (const float*)d_in[24];
    const float* efc2w = (const float*)d_in[25]; const float* efc2b = (const float*)d_in[26];

    char* base = (char*)d_ws;
    size_t off_b = 0;
    auto alloc = [&](size_t bytes)->char*{
        char* p = base + off_b;
        off_b += (bytes + 255) & ~(size_t)255;
        return p;
    };
    float* vecs = (float*)alloc(1280*4);
    u16*   Wf   = (u16*)  alloc(5*16384*2);
    float* el1 = (float*)alloc(N_K*4);
    float* el2 = (float*)alloc(N_E*4);
    float* el3 = (float*)alloc(N_K*4);
    float* el4 = (float*)alloc(N_E*4);
    float* el5 = (float*)alloc(N_U*4);
    float* erc = (float*)alloc((size_t)N_TOT*4);
    int* cnt  = (int*)alloc((size_t)N_TOT*4);
    int* offA = (int*)alloc((size_t)N_TOT*4);
    int* bsum = (int*)alloc(1024*4);
    int* btot = (int*)alloc(NBKT*4);
    int* bbase= (int*)alloc(NBKT*4);
    int2* sorted2 = (int2*)alloc((size_t)E_TOT*8);   // {src, ev}
    // union block: records+hist (CSR build) alias agg (aggregation onward)
    char* ublock = alloc((size_t)PTOT*128*2);        // 61.5 MB
    uint2* rec = (uint2*)ublock;                     // 17.6 MB, dead after bkt_fill
    int* hist  = (int*)(ublock + (size_t)E_TOT*8);   // 790 KB, dead after bkt_scatter
    u16* agg   = (u16*)ublock;
    u16* knb   = (u16*)alloc((size_t)N_K*128*2);
    u16* exerb = (u16*)alloc((size_t)N_E*128*2);
    u16* stub  = (u16*)alloc((size_t)N_U*128*2);
    size_t need_bf = off_b;
    bool useBF = (ws_size >= need_bf);
    float* out = (float*)d_out;

    const int NBLK = (N_TOT + 255)/256;     // 938 (<=1024 for scan2)

    // weight prep (vecs + MFMA fragments), wide grid
    prep_w<<<360,256,0,stream>>>(W_und,W_ek,W_ke,W_eu,W_ue, a_und,a_ek,a_ke,a_eu,a_ue, vecs, Wf);

    // fused conv(f32->bf16) + el/er dots; er goes straight into erc at key bases
    if (useBF){
        conv_dot<4,1><<<(N_K+3)/4,256,0,stream>>>(kn,   knb,   vecs+0,    vecs+640, vecs+768,  vecs+256,  el1, erc+KB1, erc+KB2, el3, N_K);
        conv_dot<4,1><<<(N_E+3)/4,256,0,stream>>>(exer, exerb, vecs+128,  vecs+896, vecs+384,  vecs+1152, el2, erc+KB3, el4, erc+KB5, N_E);
        conv_dot<2,1><<<(N_U+3)/4,256,0,stream>>>(stu,  stub,  vecs+1024, vecs+512, nullptr, nullptr, erc+KB4, el5, nullptr, nullptr, N_U);
    } else {
        conv_dot<4,0><<<(N_K+3)/4,256,0,stream>>>(kn,   nullptr, vecs+0,    vecs+640, vecs+768,  vecs+256,  el1, erc+KB1, erc+KB2, el3, N_K);
        conv_dot<4,0><<<(N_E+3)/4,256,0,stream>>>(exer, nullptr, vecs+128,  vecs+896, vecs+384,  vecs+1152, el2, erc+KB3, el4, erc+KB5, N_E);
        conv_dot<2,0><<<(N_U+3)/4,256,0,stream>>>(stu,  nullptr, vecs+1024, vecs+512, nullptr, nullptr, erc+KB4, el5, nullptr, nullptr, N_U);
    }

    // atomic-free CSR build (bucket counting sort)
    bkt_hist<<<NBLKA,256,0,stream>>>(und_dst, ek_src, ek_dst, eu_src, eu_dst, hist);
    bkt_scan1<<<NBKT,512,0,stream>>>(hist, btot);
    bkt_scan2<<<1,1024,0,stream>>>(btot, bbase);
    bkt_scatter<<<NBLKA,256,0,stream>>>(und_src, und_dst, ek_src, ek_dst, eu_src, eu_dst,
                                        hist, bbase, rec);
    bkt_cnt<<<NBKT,256,0,stream>>>(rec, bbase, btot, cnt);
    scan1<<<NBLK,256,0,stream>>>(cnt, offA, bsum, N_TOT);
    scan2<<<1,1024,0,stream>>>(bsum, NBLK);
    scan3<<<NBLK,256,0,stream>>>(offA, bsum, N_TOT);
    bkt_fill<<<NBKT,256,0,stream>>>(rec, bbase, btot, offA, erc,
                                    el1, el2, el3, el4, el5, sorted2);

    if (useBF){
        aggregate_all<1><<<(PTOT+3)/4,256,0,stream>>>(cnt, offA, sorted2, knb, exerb, stub, agg);
        gemm_epi<1><<<KBLK+EBLK+SBLK,256,0,stream>>>(agg, Wf, knb, exerb, stub,
                                                     kfc2w,kfc2b,kfc3w,kfc3b,
                                                     efc1w,efc1b,efc2w,efc2b, out);
    } else {
        aggregate_all<0><<<(PTOT+3)/4,256,0,stream>>>(cnt, offA, sorted2, kn, exer, stu, agg);
        gemm_epi<0><<<KBLK+EBLK+SBLK,256,0,stream>>>(agg, Wf, kn, exer, stu,
                                                     kfc2w,kfc2b,kfc3w,kfc3b,
                                                     efc1w,efc1b,efc2w,efc2b, out);
    }
}

// Round 9
// 308.614 us; speedup vs baseline: 1.4130x; 1.0002x over previous
//
#include <hip/hip_runtime.h>

#define N_K 20000
#define N_E 50000
#define N_U 100000
#define E_TOT 2200000
#define N_TOT 240000
// key-space (concat dst) bases
#define KB1 0
#define KB2 20000
#define KB3 40000
#define KB4 90000
#define KB5 190000
// bucket sort geometry
#define NBKT 726
#define EPB 8192
#define NBLKA 269          // ceil(E_TOT / EPB)
#define APAD 272
// fused agg+gemm block counts (16 nodes per block; all sizes % 16 == 0)
#define KN_B 1250
#define EX_B 3125
#define ST_B 6250

typedef unsigned short u16;
typedef unsigned int u32;
typedef __bf16 bf16x8 __attribute__((ext_vector_type(8)));
typedef float f32x4 __attribute__((ext_vector_type(4)));

__device__ __forceinline__ float bf2f(u16 v){
    union { u32 u; float f; } x; x.u = ((u32)v) << 16; return x.f;
}
__device__ __forceinline__ u16 f2bf(float f){
    union { float f; u32 u; } x; x.f = f;
    u32 r = x.u + 0x7FFFu + ((x.u >> 16) & 1u);
    return (u16)(r >> 16);
}
__device__ __forceinline__ float leaky_exp(float x){
    x = x >= 0.f ? x : 0.01f*x;
    return __expf(x);
}

// bucket mapping: per-range shifts, each bucket <=512 keys
__device__ __forceinline__ int bucket_of(int key){
    if (key < 20000)  return key >> 8;
    if (key < 40000)  return 79  + ((key - 20000) >> 7);
    if (key < 90000)  return 236 + ((key - 40000) >> 9);
    if (key < 190000) return 334 + ((key - 90000) >> 9);
    return 530 + ((key - 190000) >> 8);
}
__device__ __forceinline__ void bucket_info(int b, int& kb, int& w, int& r){
    if (b < 79){       r=0; kb = b << 8;                 w = min(256, 20000  - kb); }
    else if (b < 236){ r=1; kb = 20000 + ((b-79)  << 7); w = min(128, 40000  - kb); }
    else if (b < 334){ r=2; kb = 40000 + ((b-236) << 9); w = min(512, 90000  - kb); }
    else if (b < 530){ r=3; kb = 90000 + ((b-334) << 9); w = min(512, 190000 - kb); }
    else {             r=4; kb = 190000 + ((b-530) << 8); w = min(256, 240000 - kb); }
}
__device__ __forceinline__ int edge_key(int e,
    const int* ud, const int* es, const int* ed, const int* vs, const int* vd){
    if (e < 200000)  return ud[e];
    if (e < 600000)  return 20000  + ed[e-200000];
    if (e < 1000000) return 40000  + es[e-600000];
    if (e < 1600000) return 90000  + vd[e-1000000];
    return 190000 + vs[e-1600000];
}
__device__ __forceinline__ int edge_src(int e,
    const int* us, const int* es, const int* ed, const int* vs, const int* vd){
    if (e < 200000)  return us[e];
    if (e < 600000)  return es[e-200000];
    if (e < 1000000) return ed[e-600000];
    if (e < 1600000) return vs[e-1000000];
    return vd[e-1600000];
}

// ------------------------------------------------- fused weight prep (vecs + MFMA frags)
__global__ __launch_bounds__(256) void prep_w(
    const float* W0, const float* W1, const float* W2, const float* W3, const float* W4,
    const float* a0, const float* a1, const float* a2, const float* a3, const float* a4,
    float* __restrict__ vecs, u16* __restrict__ Wf)
{
    int bid = blockIdx.x;
    if (bid < 320){
        int o = bid*4 + (threadIdx.x >> 6);
        int lane = threadIdx.x & 63;
        int which = o / 640, rem = o - which*640, g = rem >> 7, k = rem & 127;
        const float* W = g==0?W0:g==1?W1:g==2?W2:g==3?W3:W4;
        const float* a = g==0?a0:g==1?a1:g==2?a2:g==3?a3:a4;
        const float* av = a + which*128;
        int c = lane*2;
        float s = W[k*128 + c]*av[c] + W[k*128 + c + 1]*av[c+1];
        #pragma unroll
        for (int m = 32; m; m >>= 1) s += __shfl_xor(s, m);
        if (lane == 0) vecs[(which*5 + g)*128 + k] = s;
    } else {
        int t = (bid - 320)*256 + threadIdx.x;   // 0..10239
        int g = t / 2048, i = t - g*2048;
        const float* W = g==0?W0:g==1?W1:g==2?W2:g==3?W3:W4;
        int lane = i & 63, tt = i >> 6, ks = tt & 3, ct = tt >> 2;
        int kbase = ks*32 + (lane>>4)*8;
        int c = ct*16 + (lane&15);
        #pragma unroll
        for (int j = 0; j < 8; ++j)
            Wf[g*16384 + i*8 + j] = f2bf(W[(kbase+j)*128 + c]);
    }
}

// ------------------------------------------------- fused conv(f32->bf16) + row dots (all 3 matrices)
template<int WBF>
__global__ __launch_bounds__(256) void conv_all(
    const float* __restrict__ kn, const float* __restrict__ exer, const float* __restrict__ stu,
    u16* __restrict__ knb, u16* __restrict__ exerb, u16* __restrict__ stub,
    const float* __restrict__ vecs,
    float* __restrict__ el1, float* __restrict__ el2, float* __restrict__ el3,
    float* __restrict__ el4, float* __restrict__ el5, float* __restrict__ erc)
{
    int w = (int)((blockIdx.x*(u32)blockDim.x + threadIdx.x) >> 6);
    int lane = threadIdx.x & 63;
    if (w >= 170000) return;
    const float* h; u16* hb; int local, nd;
    const float *v0,*v1,*v2,*v3;
    float *o0,*o1,*o2,*o3;
    if (w < 20000){
        local = w; h = kn; hb = knb; nd = 4;
        v0=vecs+0;    v1=vecs+640;  v2=vecs+768;  v3=vecs+256;
        o0=el1; o1=erc+KB1; o2=erc+KB2; o3=el3;
    } else if (w < 70000){
        local = w - 20000; h = exer; hb = exerb; nd = 4;
        v0=vecs+128;  v1=vecs+896;  v2=vecs+384;  v3=vecs+1152;
        o0=el2; o1=erc+KB3; o2=el4; o3=erc+KB5;
    } else {
        local = w - 70000; h = stu; hb = stub; nd = 2;
        v0=vecs+1024; v1=vecs+512;  v2=vecs;      v3=vecs;
        o0=erc+KB4; o1=el5; o2=nullptr; o3=nullptr;
    }
    float2 hv = *(const float2*)(h + (size_t)local*128 + lane*2);
    if (WBF)
        *(u32*)(hb + (size_t)local*128 + lane*2) = (u32)f2bf(hv.x) | ((u32)f2bf(hv.y) << 16);
    int c = lane*2;
    float d0 = hv.x*v0[c] + hv.y*v0[c+1];
    float d1 = hv.x*v1[c] + hv.y*v1[c+1];
    float d2 = hv.x*v2[c] + hv.y*v2[c+1];
    float d3 = hv.x*v3[c] + hv.y*v3[c+1];
    #pragma unroll
    for (int o = 32; o; o >>= 1){
        d0 += __shfl_xor(d0, o); d1 += __shfl_xor(d1, o);
        d2 += __shfl_xor(d2, o); d3 += __shfl_xor(d3, o);
    }
    if (lane == 0){
        o0[local] = d0; o1[local] = d1;
        if (nd == 4){ o2[local] = d2; o3[local] = d3; }
    }
}

// ------------------------------------------------- atomic-free CSR build
__global__ __launch_bounds__(256) void bkt_hist(
    const int* __restrict__ ud, const int* __restrict__ es, const int* __restrict__ ed,
    const int* __restrict__ vs, const int* __restrict__ vd, int* __restrict__ hist)
{
    __shared__ int h[NBKT];
    for (int i = threadIdx.x; i < NBKT; i += 256) h[i] = 0;
    __syncthreads();
    int base = blockIdx.x * EPB;
    #pragma unroll 4
    for (int it = 0; it < EPB/256; ++it){
        int e = base + it*256 + threadIdx.x;
        if (e < E_TOT){
            int key = edge_key(e, ud, es, ed, vs, vd);
            atomicAdd(&h[bucket_of(key)], 1);
        }
    }
    __syncthreads();
    for (int i = threadIdx.x; i < NBKT; i += 256)
        hist[i*APAD + blockIdx.x] = h[i];
}

__global__ __launch_bounds__(512) void bkt_scan1(int* __restrict__ hist, int* __restrict__ btot)
{
    __shared__ int sm[512];
    int t = threadIdx.x;
    int v = (t < NBLKA) ? hist[blockIdx.x*APAD + t] : 0;
    sm[t] = v; __syncthreads();
    #pragma unroll
    for (int d = 1; d < 512; d <<= 1){
        int x = (t >= d) ? sm[t-d] : 0;
        __syncthreads();
        sm[t] += x;
        __syncthreads();
    }
    if (t < NBLKA) hist[blockIdx.x*APAD + t] = sm[t] - v;
    if (t == 511) btot[blockIdx.x] = sm[511];
}

__global__ __launch_bounds__(1024) void bkt_scan2(const int* __restrict__ btot, int* __restrict__ bbase)
{
    __shared__ int sm[1024];
    int t = threadIdx.x;
    int v = (t < NBKT) ? btot[t] : 0;
    sm[t] = v; __syncthreads();
    #pragma unroll
    for (int d = 1; d < 1024; d <<= 1){
        int x = (t >= d) ? sm[t-d] : 0;
        __syncthreads();
        sm[t] += x;
        __syncthreads();
    }
    if (t < NBKT) bbase[t] = sm[t] - v;
}

__global__ __launch_bounds__(256) void bkt_scatter(
    const int* __restrict__ us, const int* __restrict__ ud,
    const int* __restrict__ es, const int* __restrict__ ed,
    const int* __restrict__ vs, const int* __restrict__ vd,
    const int* __restrict__ hist, const int* __restrict__ bbase,
    uint2* __restrict__ rec)
{
    __shared__ int cur[NBKT];
    for (int i = threadIdx.x; i < NBKT; i += 256)
        cur[i] = bbase[i] + hist[i*APAD + blockIdx.x];
    __syncthreads();
    int base = blockIdx.x * EPB;
    #pragma unroll 4
    for (int it = 0; it < EPB/256; ++it){
        int e = base + it*256 + threadIdx.x;
        if (e < E_TOT){
            int key = edge_key(e, ud, es, ed, vs, vd);
            int src = edge_src(e, us, es, ed, vs, vd);
            int pos = atomicAdd(&cur[bucket_of(key)], 1);
            rec[pos] = make_uint2((u32)src, (u32)key);
        }
    }
}

// one kernel: per-bucket key hist + ev-sum -> cnt, offA (bbase + LDS scan),
// then place {src, alpha=ev/sum} into sorted2. No global atomics, no global scan.
__global__ __launch_bounds__(512) void bkt_finalize(const uint2* __restrict__ rec,
    const int* __restrict__ bbase, const int* __restrict__ btot,
    const float* __restrict__ erc,
    const float* __restrict__ el1, const float* __restrict__ el2,
    const float* __restrict__ el3, const float* __restrict__ el4,
    const float* __restrict__ el5,
    int* __restrict__ cnt, int* __restrict__ offA, int2* __restrict__ sorted2)
{
    __shared__ int   h[512];
    __shared__ float s[512];
    __shared__ float ercs[512];
    __shared__ int   sm[512];
    __shared__ int   curk[512];
    int b = blockIdx.x, t = threadIdx.x;
    int kb, w, r;
    bucket_info(b, kb, w, r);
    h[t] = 0; s[t] = 0.f;
    if (t < w) ercs[t] = erc[kb + t];
    __syncthreads();
    const float* el = r==0?el1 : r==1?el2 : r==2?el3 : r==3?el4 : el5;
    int start = bbase[b], n = btot[b];
    for (int i = t; i < n; i += 512){
        uint2 rc = rec[start + i];
        int local = (int)rc.y - kb;
        atomicAdd(&h[local], 1);
        atomicAdd(&s[local], leaky_exp(el[rc.x] + ercs[local]));
    }
    __syncthreads();
    int hv = h[t];
    if (t < w) cnt[kb + t] = hv;
    sm[t] = hv; __syncthreads();
    #pragma unroll
    for (int d = 1; d < 512; d <<= 1){
        int x = (t >= d) ? sm[t-d] : 0;
        __syncthreads();
        sm[t] += x;
        __syncthreads();
    }
    int pos0 = start + sm[t] - hv;
    if (t < w) offA[kb + t] = pos0;
    curk[t] = pos0;
    __syncthreads();
    for (int i = t; i < n; i += 512){
        uint2 rc = rec[start + i];
        int local = (int)rc.y - kb;
        float alpha = leaky_exp(el[rc.x] + ercs[local]) / s[local];
        int pos = atomicAdd(&curk[local], 1);
        sorted2[pos] = make_int2((int)rc.x, __float_as_int(alpha));
    }
}

// ------------------------------------------------- fused aggregation + dual-GEMM + epilogue
// Block = 16 nodes. Waves aggregate segC(+segD) rows into LDS (bf16, padded
// [16][136] rows -> 16B-aligned ds_read_b128, 2-way bank alias only), then
// each wave MFMAs its 2 column-tiles for C (and D), gating via shfl partials
// + LDS float adds, writes f32 d_out. agg never touches global memory.
template<int BF>
__global__ __launch_bounds__(256) void agg_gemm_epi(
    const int* __restrict__ cnt, const int* __restrict__ offA, const int2* __restrict__ sorted2,
    const void* __restrict__ hk, const void* __restrict__ he, const void* __restrict__ hs,
    const u16* __restrict__ Wf,
    const float* __restrict__ kfc2w, const float* __restrict__ kfc2b,
    const float* __restrict__ kfc3w, const float* __restrict__ kfc3b,
    const float* __restrict__ efc1w, const float* __restrict__ efc1b,
    const float* __restrict__ efc2w, const float* __restrict__ efc2b,
    float* __restrict__ out)
{
    __shared__ u16 ldsC[16*136];
    __shared__ u16 ldsD[16*136];
    __shared__ float sred2[16], sred3[16], p2s[16], p3s[16];

    int bid = blockIdx.x;
    int wave = threadIdx.x >> 6, lane = threadIdx.x & 63;
    int kind, node0, keyC, keyD;
    const void *hC, *hD, *Aseg;
    const u16 *wc, *wd;
    const float *w2, *b2, *w3, *b3;
    float* outp;
    if (bid < KN_B){
        kind=0; node0 = bid*16;
        keyC = KB1 + node0; keyD = KB2 + node0;
        hC = hk; hD = he; Aseg = hk;
        wc = Wf; wd = Wf + 16384;
        w2=kfc2w; b2=kfc2b; w3=kfc3w; b3=kfc3b;
        outp = out;
    } else if (bid < KN_B + EX_B){
        kind=0; node0 = (bid - KN_B)*16;
        keyC = KB3 + node0; keyD = KB5 + node0;
        hC = hk; hD = hs; Aseg = he;
        wc = Wf + 2*16384; wd = Wf + 4*16384;
        w2=efc1w; b2=efc1b; w3=efc2w; b3=efc2b;
        outp = out + (size_t)N_K*128;
    } else {
        kind=1; node0 = (bid - KN_B - EX_B)*16;
        keyC = KB4 + node0; keyD = 0;
        hC = he; hD = nullptr; Aseg = hs;
        wc = Wf + 3*16384; wd = nullptr;
        w2=nullptr; b2=nullptr; w3=nullptr; b3=nullptr;
        outp = out + (size_t)(N_K + N_E)*128;
    }

    // ---- aggregation into LDS ----
    int rpw = (kind == 0) ? 8 : 4;       // combined rows per wave
    for (int rr = 0; rr < rpw; ++rr){
        int c = wave*rpw + rr;           // 0..31 (kn/exer) or 0..15 (stu)
        int seg = c >> 4, nd = c & 15;
        int key = (seg == 0 ? keyC : keyD) + nd;
        const u32* hb32 = (const u32*)(seg == 0 ? hC : hD);
        const float2* hf2 = (const float2*)(seg == 0 ? hC : hD);
        int deg = cnt[key], start = offA[key];
        float a0 = 0.f, a1 = 0.f;
        int i = 0;
        for (; i + 8 <= deg; i += 8){
            int2 w[8];
            #pragma unroll
            for (int j = 0; j < 8; ++j) w[j] = sorted2[start+i+j];
            if (BF){
                u32 hv[8];
                #pragma unroll
                for (int j = 0; j < 8; ++j) hv[j] = hb32[(size_t)w[j].x*64 + lane];
                #pragma unroll
                for (int j = 0; j < 8; ++j){
                    float al = __int_as_float(w[j].y);
                    a0 = fmaf(al, bf2f((u16)hv[j]), a0);
                    a1 = fmaf(al, bf2f((u16)(hv[j]>>16)), a1);
                }
            } else {
                float2 hv[8];
                #pragma unroll
                for (int j = 0; j < 8; ++j) hv[j] = hf2[(size_t)w[j].x*64 + lane];
                #pragma unroll
                for (int j = 0; j < 8; ++j){
                    float al = __int_as_float(w[j].y);
                    a0 = fmaf(al, hv[j].x, a0);
                    a1 = fmaf(al, hv[j].y, a1);
                }
            }
        }
        for (; i + 4 <= deg; i += 4){
            int2 w[4];
            #pragma unroll
            for (int j = 0; j < 4; ++j) w[j] = sorted2[start+i+j];
            if (BF){
                u32 hv[4];
                #pragma unroll
                for (int j = 0; j < 4; ++j) hv[j] = hb32[(size_t)w[j].x*64 + lane];
                #pragma unroll
                for (int j = 0; j < 4; ++j){
                    float al = __int_as_float(w[j].y);
                    a0 = fmaf(al, bf2f((u16)hv[j]), a0);
                    a1 = fmaf(al, bf2f((u16)(hv[j]>>16)), a1);
                }
            } else {
                float2 hv[4];
                #pragma unroll
                for (int j = 0; j < 4; ++j) hv[j] = hf2[(size_t)w[j].x*64 + lane];
                #pragma unroll
                for (int j = 0; j < 4; ++j){
                    float al = __int_as_float(w[j].y);
                    a0 = fmaf(al, hv[j].x, a0);
                    a1 = fmaf(al, hv[j].y, a1);
                }
            }
        }
        for (; i < deg; ++i){
            int2 w = sorted2[start + i];
            float al = __int_as_float(w.y);
            if (BF){
                u32 hv = hb32[(size_t)w.x*64 + lane];
                a0 = fmaf(al, bf2f((u16)hv), a0);
                a1 = fmaf(al, bf2f((u16)(hv>>16)), a1);
            } else {
                float2 hv = hf2[(size_t)w.x*64 + lane];
                a0 = fmaf(al, hv.x, a0);
                a1 = fmaf(al, hv.y, a1);
            }
        }
        u16* dstl = (seg == 0 ? ldsC : ldsD) + nd*136 + lane*2;
        *(u32*)dstl = (u32)f2bf(a0) | ((u32)f2bf(a1) << 16);
    }
    if (threadIdx.x < 16){ sred2[threadIdx.x] = 0.f; sred3[threadIdx.x] = 0.f; }
    __syncthreads();

    // ---- GEMM phase: wave handles ct = 2*wave, 2*wave+1 ----
    int colb = lane & 15, rlo = (lane >> 4)*4;
    const float* Af = (const float*)Aseg;
    const u16*   Ab = (const u16*)Aseg;

    bf16x8 afC[4];
    #pragma unroll
    for (int ks = 0; ks < 4; ++ks)
        afC[ks] = *(const bf16x8*)(ldsC + (lane & 15)*136 + ks*32 + (lane >> 4)*8);
    f32x4 accC[2];
    accC[0] = (f32x4){0.f,0.f,0.f,0.f}; accC[1] = (f32x4){0.f,0.f,0.f,0.f};
    #pragma unroll
    for (int ci = 0; ci < 2; ++ci){
        int ct = wave*2 + ci;
        #pragma unroll
        for (int ks = 0; ks < 4; ++ks){
            bf16x8 bfr = *(const bf16x8*)(wc + ((ct*4+ks)*64 + lane)*8);
            accC[ci] = __builtin_amdgcn_mfma_f32_16x16x32_bf16(afC[ks], bfr, accC[ci], 0, 0, 0);
        }
    }

    if (kind == 1){
        #pragma unroll
        for (int ci = 0; ci < 2; ++ci){
            int ct = wave*2 + ci;
            #pragma unroll
            for (int j = 0; j < 4; ++j){
                size_t idx = (size_t)(node0 + rlo + j)*128 + ct*16 + colb;
                float av = BF ? bf2f(Ab[idx]) : Af[idx];
                outp[idx] = accC[ci][j] + av;
            }
        }
        return;
    }

    bf16x8 afD[4];
    #pragma unroll
    for (int ks = 0; ks < 4; ++ks)
        afD[ks] = *(const bf16x8*)(ldsD + (lane & 15)*136 + ks*32 + (lane >> 4)*8);
    f32x4 accD[2];
    accD[0] = (f32x4){0.f,0.f,0.f,0.f}; accD[1] = (f32x4){0.f,0.f,0.f,0.f};
    #pragma unroll
    for (int ci = 0; ci < 2; ++ci){
        int ct = wave*2 + ci;
        #pragma unroll
        for (int ks = 0; ks < 4; ++ks){
            bf16x8 bfr = *(const bf16x8*)(wd + ((ct*4+ks)*64 + lane)*8);
            accD[ci] = __builtin_amdgcn_mfma_f32_16x16x32_bf16(afD[ks], bfr, accD[ci], 0, 0, 0);
        }
    }

    // gating partials for this wave's 2 column-tiles
    float aA[2][4];
    float s2p[4] = {0.f,0.f,0.f,0.f}, s3p[4] = {0.f,0.f,0.f,0.f};
    #pragma unroll
    for (int ci = 0; ci < 2; ++ci){
        int ct = wave*2 + ci;
        float w2l = w2[ct*16 + colb], w2h = w2[128 + ct*16 + colb];
        float w3l = w3[ct*16 + colb], w3h = w3[128 + ct*16 + colb];
        #pragma unroll
        for (int j = 0; j < 4; ++j){
            size_t idx = (size_t)(node0 + rlo + j)*128 + ct*16 + colb;
            float av = BF ? bf2f(Ab[idx]) : Af[idx];
            aA[ci][j] = av;
            s2p[j] = fmaf(av, w2l, fmaf(accC[ci][j], w2h, s2p[j]));
            s3p[j] = fmaf(av, w3l, fmaf(accD[ci][j], w3h, s3p[j]));
        }
    }
    #pragma unroll
    for (int m = 8; m; m >>= 1)
        #pragma unroll
        for (int j = 0; j < 4; ++j){
            s2p[j] += __shfl_xor(s2p[j], m);
            s3p[j] += __shfl_xor(s3p[j], m);
        }
    if (colb == 0){
        #pragma unroll
        for (int j = 0; j < 4; ++j){
            atomicAdd(&sred2[rlo + j], s2p[j]);
            atomicAdd(&sred3[rlo + j], s3p[j]);
        }
    }
    __syncthreads();
    if (threadIdx.x < 16){
        float s2 = sred2[threadIdx.x] + b2[0];
        float s3 = sred3[threadIdx.x] + b3[0];
        float mx = fmaxf(s2, s3);
        float e2 = __expf(s2 - mx), e3 = __expf(s3 - mx);
        float inv = 1.f/(e2 + e3);
        p2s[threadIdx.x] = e2*inv;
        p3s[threadIdx.x] = e3*inv;
    }
    __syncthreads();
    #pragma unroll
    for (int ci = 0; ci < 2; ++ci){
        int ct = wave*2 + ci;
        #pragma unroll
        for (int j = 0; j < 4; ++j){
            int row = rlo + j;
            size_t idx = (size_t)(node0 + row)*128 + ct*16 + colb;
            outp[idx] = aA[ci][j] + p2s[row]*accC[ci][j] + p3s[row]*accD[ci][j];
        }
    }
}

extern "C" void kernel_launch(void* const* d_in, const int* in_sizes, int n_in,
                              void* d_out, int out_size, void* d_ws, size_t ws_size,
                              hipStream_t stream)
{
    (void)in_sizes; (void)n_in; (void)out_size;
    const float* kn   = (const float*)d_in[0];
    const float* exer = (const float*)d_in[1];
    const float* stu  = (const float*)d_in[2];
    const int* und_src = (const int*)d_in[3];
    const int* und_dst = (const int*)d_in[4];
    const int* ek_src  = (const int*)d_in[5];
    const int* ek_dst  = (const int*)d_in[6];
    const int* eu_src  = (const int*)d_in[7];
    const int* eu_dst  = (const int*)d_in[8];
    const float* W_und = (const float*)d_in[9];  const float* a_und = (const float*)d_in[10];
    const float* W_ek  = (const float*)d_in[11]; const float* a_ek  = (const float*)d_in[12];
    const float* W_ke  = (const float*)d_in[13]; const float* a_ke  = (const float*)d_in[14];
    const float* W_eu  = (const float*)d_in[15]; const float* a_eu  = (const float*)d_in[16];
    const float* W_ue  = (const float*)d_in[17]; const float* a_ue  = (const float*)d_in[18];
    const float* kfc2w = (const float*)d_in[19]; const float* kfc2b = (const float*)d_in[20];
    const float* kfc3w = (const float*)d_in[21]; const float* kfc3b = (const float*)d_in[22];
    const float* efc1w = (const float*)d_in[23]; const float* efc1b = (const float*)d_in[24];
    const float* efc2w = (const float*)d_in[25]; const float* efc2b = (const float*)d_in[26];

    char* base = (char*)d_ws;
    size_t off_b = 0;
    auto alloc = [&](size_t bytes)->char*{
        char* p = base + off_b;
        off_b += (bytes + 255) & ~(size_t)255;
        return p;
    };
    float* vecs = (float*)alloc(1280*4);
    u16*   Wf   = (u16*)  alloc(5*16384*2);
    float* el1 = (float*)alloc(N_K*4);
    float* el2 = (float*)alloc(N_E*4);
    float* el3 = (float*)alloc(N_K*4);
    float* el4 = (float*)alloc(N_E*4);
    float* el5 = (float*)alloc(N_U*4);
    float* erc = (float*)alloc((size_t)N_TOT*4);
    int* cnt  = (int*)alloc((size_t)N_TOT*4);
    int* offA = (int*)alloc((size_t)N_TOT*4);
    int* btot = (int*)alloc(NBKT*4);
    int* bbase= (int*)alloc(NBKT*4);
    int* hist = (int*)alloc((size_t)NBKT*APAD*4);
    uint2* rec = (uint2*)alloc((size_t)E_TOT*8);
    int2* sorted2 = (int2*)alloc((size_t)E_TOT*8);   // {src, alpha}
    u16* knb   = (u16*)alloc((size_t)N_K*128*2);
    u16* exerb = (u16*)alloc((size_t)N_E*128*2);
    u16* stub  = (u16*)alloc((size_t)N_U*128*2);
    size_t need_bf = off_b;
    bool useBF = (ws_size >= need_bf);
    float* out = (float*)d_out;

    prep_w<<<360,256,0,stream>>>(W_und,W_ek,W_ke,W_eu,W_ue, a_und,a_ek,a_ke,a_eu,a_ue, vecs, Wf);

    if (useBF)
        conv_all<1><<<(170000+3)/4,256,0,stream>>>(kn, exer, stu, knb, exerb, stub, vecs,
                                                   el1, el2, el3, el4, el5, erc);
    else
        conv_all<0><<<(170000+3)/4,256,0,stream>>>(kn, exer, stu, knb, exerb, stub, vecs,
                                                   el1, el2, el3, el4, el5, erc);

    bkt_hist<<<NBLKA,256,0,stream>>>(und_dst, ek_src, ek_dst, eu_src, eu_dst, hist);
    bkt_scan1<<<NBKT,512,0,stream>>>(hist, btot);
    bkt_scan2<<<1,1024,0,stream>>>(btot, bbase);
    bkt_scatter<<<NBLKA,256,0,stream>>>(und_src, und_dst, ek_src, ek_dst, eu_src, eu_dst,
                                        hist, bbase, rec);
    bkt_finalize<<<NBKT,512,0,stream>>>(rec, bbase, btot, erc,
                                        el1, el2, el3, el4, el5,
                                        cnt, offA, sorted2);

    if (useBF){
        agg_gemm_epi<1><<<KN_B+EX_B+ST_B,256,0,stream>>>(cnt, offA, sorted2,
            knb, exerb, stub, Wf,
            kfc2w,kfc2b,kfc3w,kfc3b, efc1w,efc1b,efc2w,efc2b, out);
    } else {
        agg_gemm_epi<0><<<KN_B+EX_B+ST_B,256,0,stream>>>(cnt, offA, sorted2,
            kn, exer, stu, Wf,
            kfc2w,kfc2b,kfc3w,kfc3b, efc1w,efc1b,efc2w,efc2b, out);
    }
}

// Round 10
// 299.394 us; speedup vs baseline: 1.4566x; 1.0308x over previous
//
#include <hip/hip_runtime.h>
#include <hip/hip_fp8.h>

#define N_K 20000
#define N_E 50000
#define N_U 100000
#define E_TOT 2200000
#define N_TOT 240000
// key-space (concat dst) bases
#define KB1 0
#define KB2 20000
#define KB3 40000
#define KB4 90000
#define KB5 190000
// bucket sort geometry
#define NBKT 726
#define EPB 8192
#define NBLKA 269          // ceil(E_TOT / EPB)
#define APAD 272
// fused agg+gemm block counts (16 nodes per block)
#define KN_B 1250
#define EX_B 3125
#define ST_B 6250

typedef unsigned short u16;
typedef unsigned int u32;
typedef unsigned char u8;
typedef __bf16 bf16x8 __attribute__((ext_vector_type(8)));
typedef float f32x4 __attribute__((ext_vector_type(4)));

__device__ __forceinline__ float bf2f(u16 v){
    union { u32 u; float f; } x; x.u = ((u32)v) << 16; return x.f;
}
__device__ __forceinline__ u16 f2bf(float f){
    union { float f; u32 u; } x; x.f = f;
    u32 r = x.u + 0x7FFFu + ((x.u >> 16) & 1u);
    return (u16)(r >> 16);
}
__device__ __forceinline__ float leaky_exp(float x){
    x = x >= 0.f ? x : 0.01f*x;
    return __expf(x);
}
// fp8 e4m3 encode/decode (HW cvt on gfx950; struct fallback). Encode+decode
// use the same HW format family -> roundtrip self-consistent.
__device__ __forceinline__ u16 fp8pk(float a, float b){
#if __has_builtin(__builtin_amdgcn_cvt_pk_fp8_f32)
    return (u16)__builtin_amdgcn_cvt_pk_fp8_f32(a, b, 0, false);
#else
    __hip_fp8_e4m3 qa(a), qb(b);
    return (u16)qa.__x | ((u16)qb.__x << 8);
#endif
}
__device__ __forceinline__ float fp8lo(u32 w){
#if __has_builtin(__builtin_amdgcn_cvt_f32_fp8)
    return __builtin_amdgcn_cvt_f32_fp8((int)w, 0);
#else
    __hip_fp8_e4m3 q; q.__x = (u8)(w & 0xFF); return (float)q;
#endif
}
__device__ __forceinline__ float fp8hi(u32 w){
#if __has_builtin(__builtin_amdgcn_cvt_f32_fp8)
    return __builtin_amdgcn_cvt_f32_fp8((int)w, 1);
#else
    __hip_fp8_e4m3 q; q.__x = (u8)((w >> 8) & 0xFF); return (float)q;
#endif
}

// bucket mapping: per-range shifts, each bucket <=512 keys
__device__ __forceinline__ int bucket_of(int key){
    if (key < 20000)  return key >> 8;
    if (key < 40000)  return 79  + ((key - 20000) >> 7);
    if (key < 90000)  return 236 + ((key - 40000) >> 9);
    if (key < 190000) return 334 + ((key - 90000) >> 9);
    return 530 + ((key - 190000) >> 8);
}
__device__ __forceinline__ void bucket_info(int b, int& kb, int& w, int& r){
    if (b < 79){       r=0; kb = b << 8;                 w = min(256, 20000  - kb); }
    else if (b < 236){ r=1; kb = 20000 + ((b-79)  << 7); w = min(128, 40000  - kb); }
    else if (b < 334){ r=2; kb = 40000 + ((b-236) << 9); w = min(512, 90000  - kb); }
    else if (b < 530){ r=3; kb = 90000 + ((b-334) << 9); w = min(512, 190000 - kb); }
    else {             r=4; kb = 190000 + ((b-530) << 8); w = min(256, 240000 - kb); }
}
__device__ __forceinline__ int edge_key(int e,
    const int* ud, const int* es, const int* ed, const int* vs, const int* vd){
    if (e < 200000)  return ud[e];
    if (e < 600000)  return 20000  + ed[e-200000];
    if (e < 1000000) return 40000  + es[e-600000];
    if (e < 1600000) return 90000  + vd[e-1000000];
    return 190000 + vs[e-1600000];
}
__device__ __forceinline__ int edge_src(int e,
    const int* us, const int* es, const int* ed, const int* vs, const int* vd){
    if (e < 200000)  return us[e];
    if (e < 600000)  return es[e-200000];
    if (e < 1000000) return ed[e-600000];
    if (e < 1600000) return vs[e-1000000];
    return vd[e-1600000];
}

// ------------------------------------------------- fused weight prep (vecs + MFMA frags)
__global__ __launch_bounds__(256) void prep_w(
    const float* W0, const float* W1, const float* W2, const float* W3, const float* W4,
    const float* a0, const float* a1, const float* a2, const float* a3, const float* a4,
    float* __restrict__ vecs, u16* __restrict__ Wf)
{
    int bid = blockIdx.x;
    if (bid < 320){
        int o = bid*4 + (threadIdx.x >> 6);
        int lane = threadIdx.x & 63;
        int which = o / 640, rem = o - which*640, g = rem >> 7, k = rem & 127;
        const float* W = g==0?W0:g==1?W1:g==2?W2:g==3?W3:W4;
        const float* a = g==0?a0:g==1?a1:g==2?a2:g==3?a3:a4;
        const float* av = a + which*128;
        int c = lane*2;
        float s = W[k*128 + c]*av[c] + W[k*128 + c + 1]*av[c+1];
        #pragma unroll
        for (int m = 32; m; m >>= 1) s += __shfl_xor(s, m);
        if (lane == 0) vecs[(which*5 + g)*128 + k] = s;
    } else {
        int t = (bid - 320)*256 + threadIdx.x;   // 0..10239
        int g = t / 2048, i = t - g*2048;
        const float* W = g==0?W0:g==1?W1:g==2?W2:g==3?W3:W4;
        int lane = i & 63, tt = i >> 6, ks = tt & 3, ct = tt >> 2;
        int kbase = ks*32 + (lane>>4)*8;
        int c = ct*16 + (lane&15);
        #pragma unroll
        for (int j = 0; j < 8; ++j)
            Wf[g*16384 + i*8 + j] = f2bf(W[(kbase+j)*128 + c]);
    }
}

// ------------------------------------------------- fused conv(f32->bf16+fp8) + row dots
template<int WBF>
__global__ __launch_bounds__(256) void conv_all(
    const float* __restrict__ kn, const float* __restrict__ exer, const float* __restrict__ stu,
    u16* __restrict__ knb, u16* __restrict__ exerb, u16* __restrict__ stub,
    u8* __restrict__ knf, u8* __restrict__ exerf, u8* __restrict__ stuf,
    const float* __restrict__ vecs,
    float* __restrict__ el1, float* __restrict__ el2, float* __restrict__ el3,
    float* __restrict__ el4, float* __restrict__ el5, float* __restrict__ erc)
{
    int w = (int)((blockIdx.x*(u32)blockDim.x + threadIdx.x) >> 6);
    int lane = threadIdx.x & 63;
    if (w >= 170000) return;
    const float* h; u16* hb; u8* hf; int local, nd;
    const float *v0,*v1,*v2,*v3;
    float *o0,*o1,*o2,*o3;
    if (w < 20000){
        local = w; h = kn; hb = knb; hf = knf; nd = 4;
        v0=vecs+0;    v1=vecs+640;  v2=vecs+768;  v3=vecs+256;
        o0=el1; o1=erc+KB1; o2=erc+KB2; o3=el3;
    } else if (w < 70000){
        local = w - 20000; h = exer; hb = exerb; hf = exerf; nd = 4;
        v0=vecs+128;  v1=vecs+896;  v2=vecs+384;  v3=vecs+1152;
        o0=el2; o1=erc+KB3; o2=el4; o3=erc+KB5;
    } else {
        local = w - 70000; h = stu; hb = stub; hf = stuf; nd = 2;
        v0=vecs+1024; v1=vecs+512;  v2=vecs;      v3=vecs;
        o0=erc+KB4; o1=el5; o2=nullptr; o3=nullptr;
    }
    float2 hv = *(const float2*)(h + (size_t)local*128 + lane*2);
    if (WBF){
        *(u32*)(hb + (size_t)local*128 + lane*2) = (u32)f2bf(hv.x) | ((u32)f2bf(hv.y) << 16);
        *(u16*)(hf + (size_t)local*128 + lane*2) = fp8pk(hv.x, hv.y);
    }
    int c = lane*2;
    float d0 = hv.x*v0[c] + hv.y*v0[c+1];
    float d1 = hv.x*v1[c] + hv.y*v1[c+1];
    float d2 = hv.x*v2[c] + hv.y*v2[c+1];
    float d3 = hv.x*v3[c] + hv.y*v3[c+1];
    #pragma unroll
    for (int o = 32; o; o >>= 1){
        d0 += __shfl_xor(d0, o); d1 += __shfl_xor(d1, o);
        d2 += __shfl_xor(d2, o); d3 += __shfl_xor(d3, o);
    }
    if (lane == 0){
        o0[local] = d0; o1[local] = d1;
        if (nd == 4){ o2[local] = d2; o3[local] = d3; }
    }
}

// ------------------------------------------------- atomic-free CSR build
__global__ __launch_bounds__(256) void bkt_hist(
    const int* __restrict__ ud, const int* __restrict__ es, const int* __restrict__ ed,
    const int* __restrict__ vs, const int* __restrict__ vd, int* __restrict__ hist)
{
    __shared__ int h[NBKT];
    for (int i = threadIdx.x; i < NBKT; i += 256) h[i] = 0;
    __syncthreads();
    int base = blockIdx.x * EPB;
    #pragma unroll 4
    for (int it = 0; it < EPB/256; ++it){
        int e = base + it*256 + threadIdx.x;
        if (e < E_TOT){
            int key = edge_key(e, ud, es, ed, vs, vd);
            atomicAdd(&h[bucket_of(key)], 1);
        }
    }
    __syncthreads();
    for (int i = threadIdx.x; i < NBKT; i += 256)
        hist[i*APAD + blockIdx.x] = h[i];
}

__global__ __launch_bounds__(512) void bkt_scan1(int* __restrict__ hist, int* __restrict__ btot)
{
    __shared__ int sm[512];
    int t = threadIdx.x;
    int v = (t < NBLKA) ? hist[blockIdx.x*APAD + t] : 0;
    sm[t] = v; __syncthreads();
    #pragma unroll
    for (int d = 1; d < 512; d <<= 1){
        int x = (t >= d) ? sm[t-d] : 0;
        __syncthreads();
        sm[t] += x;
        __syncthreads();
    }
    if (t < NBLKA) hist[blockIdx.x*APAD + t] = sm[t] - v;
    if (t == 511) btot[blockIdx.x] = sm[511];
}

__global__ __launch_bounds__(1024) void bkt_scan2(const int* __restrict__ btot, int* __restrict__ bbase)
{
    __shared__ int sm[1024];
    int t = threadIdx.x;
    int v = (t < NBKT) ? btot[t] : 0;
    sm[t] = v; __syncthreads();
    #pragma unroll
    for (int d = 1; d < 1024; d <<= 1){
        int x = (t >= d) ? sm[t-d] : 0;
        __syncthreads();
        sm[t] += x;
        __syncthreads();
    }
    if (t < NBKT) bbase[t] = sm[t] - v;
}

__global__ __launch_bounds__(256) void bkt_scatter(
    const int* __restrict__ us, const int* __restrict__ ud,
    const int* __restrict__ es, const int* __restrict__ ed,
    const int* __restrict__ vs, const int* __restrict__ vd,
    const int* __restrict__ hist, const int* __restrict__ bbase,
    uint2* __restrict__ rec)
{
    __shared__ int cur[NBKT];
    for (int i = threadIdx.x; i < NBKT; i += 256)
        cur[i] = bbase[i] + hist[i*APAD + blockIdx.x];
    __syncthreads();
    int base = blockIdx.x * EPB;
    #pragma unroll 4
    for (int it = 0; it < EPB/256; ++it){
        int e = base + it*256 + threadIdx.x;
        if (e < E_TOT){
            int key = edge_key(e, ud, es, ed, vs, vd);
            int src = edge_src(e, us, es, ed, vs, vd);
            int pos = atomicAdd(&cur[bucket_of(key)], 1);
            rec[pos] = make_uint2((u32)src, (u32)key);
        }
    }
}

// per-bucket: key hist + ev-sum -> cnt/offA (bbase + LDS scan), then place
// {src, alpha=ev/sum}. Pass 1 caches ev in evb (contiguous) so pass 2 skips
// the el re-gather + exp.
__global__ __launch_bounds__(512) void bkt_finalize(const uint2* __restrict__ rec,
    const int* __restrict__ bbase, const int* __restrict__ btot,
    const float* __restrict__ erc,
    const float* __restrict__ el1, const float* __restrict__ el2,
    const float* __restrict__ el3, const float* __restrict__ el4,
    const float* __restrict__ el5, float* __restrict__ evb,
    int* __restrict__ cnt, int* __restrict__ offA, int2* __restrict__ sorted2)
{
    __shared__ int   h[512];
    __shared__ float s[512];
    __shared__ float ercs[512];
    __shared__ int   sm[512];
    __shared__ int   curk[512];
    int b = blockIdx.x, t = threadIdx.x;
    int kb, w, r;
    bucket_info(b, kb, w, r);
    h[t] = 0; s[t] = 0.f;
    if (t < w) ercs[t] = erc[kb + t];
    __syncthreads();
    const float* el = r==0?el1 : r==1?el2 : r==2?el3 : r==3?el4 : el5;
    int start = bbase[b], n = btot[b];
    for (int i = t; i < n; i += 512){
        uint2 rc = rec[start + i];
        int local = (int)rc.y - kb;
        float ev = leaky_exp(el[rc.x] + ercs[local]);
        evb[start + i] = ev;
        atomicAdd(&h[local], 1);
        atomicAdd(&s[local], ev);
    }
    __syncthreads();
    int hv = h[t];
    if (t < w) cnt[kb + t] = hv;
    sm[t] = hv; __syncthreads();
    #pragma unroll
    for (int d = 1; d < 512; d <<= 1){
        int x = (t >= d) ? sm[t-d] : 0;
        __syncthreads();
        sm[t] += x;
        __syncthreads();
    }
    int pos0 = start + sm[t] - hv;
    if (t < w) offA[kb + t] = pos0;
    curk[t] = pos0;
    __syncthreads();
    for (int i = t; i < n; i += 512){
        uint2 rc = rec[start + i];
        int local = (int)rc.y - kb;
        float alpha = evb[start + i] / s[local];
        int pos = atomicAdd(&curk[local], 1);
        sorted2[pos] = make_int2((int)rc.x, __float_as_int(alpha));
    }
}

// ------------------------------------------------- fused aggregation + dual-GEMM + epilogue
// BF=1: gathers read fp8 rows (128 B), A/residual reads bf16; BF=0: all f32.
template<int BF>
__global__ __launch_bounds__(256) void agg_gemm_epi(
    const int* __restrict__ cnt, const int* __restrict__ offA, const int2* __restrict__ sorted2,
    const void* __restrict__ hk8, const void* __restrict__ he8, const void* __restrict__ hs8,
    const void* __restrict__ knA, const void* __restrict__ exerA, const void* __restrict__ stuA,
    const u16* __restrict__ Wf,
    const float* __restrict__ kfc2w, const float* __restrict__ kfc2b,
    const float* __restrict__ kfc3w, const float* __restrict__ kfc3b,
    const float* __restrict__ efc1w, const float* __restrict__ efc1b,
    const float* __restrict__ efc2w, const float* __restrict__ efc2b,
    float* __restrict__ out)
{
    __shared__ u16 ldsC[16*136];
    __shared__ u16 ldsD[16*136];
    __shared__ float sred2[16], sred3[16], p2s[16], p3s[16];

    int bid = blockIdx.x;
    int wave = threadIdx.x >> 6, lane = threadIdx.x & 63;
    int kind, node0, keyC, keyD;
    const void *hC, *hD, *Aseg;
    const u16 *wc, *wd;
    const float *w2, *b2, *w3, *b3;
    float* outp;
    if (bid < KN_B){
        kind=0; node0 = bid*16;
        keyC = KB1 + node0; keyD = KB2 + node0;
        hC = hk8; hD = he8; Aseg = knA;
        wc = Wf; wd = Wf + 16384;
        w2=kfc2w; b2=kfc2b; w3=kfc3w; b3=kfc3b;
        outp = out;
    } else if (bid < KN_B + EX_B){
        kind=0; node0 = (bid - KN_B)*16;
        keyC = KB3 + node0; keyD = KB5 + node0;
        hC = hk8; hD = hs8; Aseg = exerA;
        wc = Wf + 2*16384; wd = Wf + 4*16384;
        w2=efc1w; b2=efc1b; w3=efc2w; b3=efc2b;
        outp = out + (size_t)N_K*128;
    } else {
        kind=1; node0 = (bid - KN_B - EX_B)*16;
        keyC = KB4 + node0; keyD = 0;
        hC = he8; hD = nullptr; Aseg = stuA;
        wc = Wf + 3*16384; wd = nullptr;
        w2=nullptr; b2=nullptr; w3=nullptr; b3=nullptr;
        outp = out + (size_t)(N_K + N_E)*128;
    }

    // ---- aggregation into LDS ----
    int rpw = (kind == 0) ? 8 : 4;       // combined rows per wave
    for (int rr = 0; rr < rpw; ++rr){
        int c = wave*rpw + rr;
        int seg = c >> 4, nd = c & 15;
        int key = (seg == 0 ? keyC : keyD) + nd;
        const u16* h16 = (const u16*)(seg == 0 ? hC : hD);    // fp8 pairs
        const float2* hf2 = (const float2*)(seg == 0 ? hC : hD);
        int deg = cnt[key], start = offA[key];
        float a0 = 0.f, a1 = 0.f;
        int i = 0;
        for (; i + 8 <= deg; i += 8){
            int2 w[8];
            #pragma unroll
            for (int j = 0; j < 8; ++j) w[j] = sorted2[start+i+j];
            if (BF){
                u32 hv[8];
                #pragma unroll
                for (int j = 0; j < 8; ++j) hv[j] = h16[(size_t)w[j].x*64 + lane];
                #pragma unroll
                for (int j = 0; j < 8; ++j){
                    float al = __int_as_float(w[j].y);
                    a0 = fmaf(al, fp8lo(hv[j]), a0);
                    a1 = fmaf(al, fp8hi(hv[j]), a1);
                }
            } else {
                float2 hv[8];
                #pragma unroll
                for (int j = 0; j < 8; ++j) hv[j] = hf2[(size_t)w[j].x*64 + lane];
                #pragma unroll
                for (int j = 0; j < 8; ++j){
                    float al = __int_as_float(w[j].y);
                    a0 = fmaf(al, hv[j].x, a0);
                    a1 = fmaf(al, hv[j].y, a1);
                }
            }
        }
        for (; i + 4 <= deg; i += 4){
            int2 w[4];
            #pragma unroll
            for (int j = 0; j < 4; ++j) w[j] = sorted2[start+i+j];
            if (BF){
                u32 hv[4];
                #pragma unroll
                for (int j = 0; j < 4; ++j) hv[j] = h16[(size_t)w[j].x*64 + lane];
                #pragma unroll
                for (int j = 0; j < 4; ++j){
                    float al = __int_as_float(w[j].y);
                    a0 = fmaf(al, fp8lo(hv[j]), a0);
                    a1 = fmaf(al, fp8hi(hv[j]), a1);
                }
            } else {
                float2 hv[4];
                #pragma unroll
                for (int j = 0; j < 4; ++j) hv[j] = hf2[(size_t)w[j].x*64 + lane];
                #pragma unroll
                for (int j = 0; j < 4; ++j){
                    float al = __int_as_float(w[j].y);
                    a0 = fmaf(al, hv[j].x, a0);
                    a1 = fmaf(al, hv[j].y, a1);
                }
            }
        }
        for (; i < deg; ++i){
            int2 w = sorted2[start + i];
            float al = __int_as_float(w.y);
            if (BF){
                u32 hv = h16[(size_t)w.x*64 + lane];
                a0 = fmaf(al, fp8lo(hv), a0);
                a1 = fmaf(al, fp8hi(hv), a1);
            } else {
                float2 hv = hf2[(size_t)w.x*64 + lane];
                a0 = fmaf(al, hv.x, a0);
                a1 = fmaf(al, hv.y, a1);
            }
        }
        u16* dstl = (seg == 0 ? ldsC : ldsD) + nd*136 + lane*2;
        *(u32*)dstl = (u32)f2bf(a0) | ((u32)f2bf(a1) << 16);
    }
    if (threadIdx.x < 16){ sred2[threadIdx.x] = 0.f; sred3[threadIdx.x] = 0.f; }
    __syncthreads();

    // ---- GEMM phase: wave handles ct = 2*wave, 2*wave+1 ----
    int colb = lane & 15, rlo = (lane >> 4)*4;
    const float* Af = (const float*)Aseg;
    const u16*   Ab = (const u16*)Aseg;

    bf16x8 afC[4];
    #pragma unroll
    for (int ks = 0; ks < 4; ++ks)
        afC[ks] = *(const bf16x8*)(ldsC + (lane & 15)*136 + ks*32 + (lane >> 4)*8);
    f32x4 accC[2];
    accC[0] = (f32x4){0.f,0.f,0.f,0.f}; accC[1] = (f32x4){0.f,0.f,0.f,0.f};
    #pragma unroll
    for (int ci = 0; ci < 2; ++ci){
        int ct = wave*2 + ci;
        #pragma unroll
        for (int ks = 0; ks < 4; ++ks){
            bf16x8 bfr = *(const bf16x8*)(wc + ((ct*4+ks)*64 + lane)*8);
            accC[ci] = __builtin_amdgcn_mfma_f32_16x16x32_bf16(afC[ks], bfr, accC[ci], 0, 0, 0);
        }
    }

    if (kind == 1){
        #pragma unroll
        for (int ci = 0; ci < 2; ++ci){
            int ct = wave*2 + ci;
            #pragma unroll
            for (int j = 0; j < 4; ++j){
                size_t idx = (size_t)(node0 + rlo + j)*128 + ct*16 + colb;
                float av = BF ? bf2f(Ab[idx]) : Af[idx];
                outp[idx] = accC[ci][j] + av;
            }
        }
        return;
    }

    bf16x8 afD[4];
    #pragma unroll
    for (int ks = 0; ks < 4; ++ks)
        afD[ks] = *(const bf16x8*)(ldsD + (lane & 15)*136 + ks*32 + (lane >> 4)*8);
    f32x4 accD[2];
    accD[0] = (f32x4){0.f,0.f,0.f,0.f}; accD[1] = (f32x4){0.f,0.f,0.f,0.f};
    #pragma unroll
    for (int ci = 0; ci < 2; ++ci){
        int ct = wave*2 + ci;
        #pragma unroll
        for (int ks = 0; ks < 4; ++ks){
            bf16x8 bfr = *(const bf16x8*)(wd + ((ct*4+ks)*64 + lane)*8);
            accD[ci] = __builtin_amdgcn_mfma_f32_16x16x32_bf16(afD[ks], bfr, accD[ci], 0, 0, 0);
        }
    }

    float aA[2][4];
    float s2p[4] = {0.f,0.f,0.f,0.f}, s3p[4] = {0.f,0.f,0.f,0.f};
    #pragma unroll
    for (int ci = 0; ci < 2; ++ci){
        int ct = wave*2 + ci;
        float w2l = w2[ct*16 + colb], w2h = w2[128 + ct*16 + colb];
        float w3l = w3[ct*16 + colb], w3h = w3[128 + ct*16 + colb];
        #pragma unroll
        for (int j = 0; j < 4; ++j){
            size_t idx = (size_t)(node0 + rlo + j)*128 + ct*16 + colb;
            float av = BF ? bf2f(Ab[idx]) : Af[idx];
            aA[ci][j] = av;
            s2p[j] = fmaf(av, w2l, fmaf(accC[ci][j], w2h, s2p[j]));
            s3p[j] = fmaf(av, w3l, fmaf(accD[ci][j], w3h, s3p[j]));
        }
    }
    #pragma unroll
    for (int m = 8; m; m >>= 1)
        #pragma unroll
        for (int j = 0; j < 4; ++j){
            s2p[j] += __shfl_xor(s2p[j], m);
            s3p[j] += __shfl_xor(s3p[j], m);
        }
    if (colb == 0){
        #pragma unroll
        for (int j = 0; j < 4; ++j){
            atomicAdd(&sred2[rlo + j], s2p[j]);
            atomicAdd(&sred3[rlo + j], s3p[j]);
        }
    }
    __syncthreads();
    if (threadIdx.x < 16){
        float s2 = sred2[threadIdx.x] + b2[0];
        float s3 = sred3[threadIdx.x] + b3[0];
        float mx = fmaxf(s2, s3);
        float e2 = __expf(s2 - mx), e3 = __expf(s3 - mx);
        float inv = 1.f/(e2 + e3);
        p2s[threadIdx.x] = e2*inv;
        p3s[threadIdx.x] = e3*inv;
    }
    __syncthreads();
    #pragma unroll
    for (int ci = 0; ci < 2; ++ci){
        int ct = wave*2 + ci;
        #pragma unroll
        for (int j = 0; j < 4; ++j){
            int row = rlo + j;
            size_t idx = (size_t)(node0 + row)*128 + ct*16 + colb;
            outp[idx] = aA[ci][j] + p2s[row]*accC[ci][j] + p3s[row]*accD[ci][j];
        }
    }
}

extern "C" void kernel_launch(void* const* d_in, const int* in_sizes, int n_in,
                              void* d_out, int out_size, void* d_ws, size_t ws_size,
                              hipStream_t stream)
{
    (void)in_sizes; (void)n_in; (void)out_size;
    const float* kn   = (const float*)d_in[0];
    const float* exer = (const float*)d_in[1];
    const float* stu  = (const float*)d_in[2];
    const int* und_src = (const int*)d_in[3];
    const int* und_dst = (const int*)d_in[4];
    const int* ek_src  = (const int*)d_in[5];
    const int* ek_dst  = (const int*)d_in[6];
    const int* eu_src  = (const int*)d_in[7];
    const int* eu_dst  = (const int*)d_in[8];
    const float* W_und = (const float*)d_in[9];  const float* a_und = (const float*)d_in[10];
    const float* W_ek  = (const float*)d_in[11]; const float* a_ek  = (const float*)d_in[12];
    const float* W_ke  = (const float*)d_in[13]; const float* a_ke  = (const float*)d_in[14];
    const float* W_eu  = (const float*)d_in[15]; const float* a_eu  = (const float*)d_in[16];
    const float* W_ue  = (const float*)d_in[17]; const float* a_ue  = (const float*)d_in[18];
    const float* kfc2w = (const float*)d_in[19]; const float* kfc2b = (const float*)d_in[20];
    const float* kfc3w = (const float*)d_in[21]; const float* kfc3b = (const float*)d_in[22];
    const float* efc1w = (const float*)d_in[23]; const float* efc1b = (const float*)d_in[24];
    const float* efc2w = (const float*)d_in[25]; const float* efc2b = (const float*)d_in[26];

    char* base = (char*)d_ws;
    size_t off_b = 0;
    auto alloc = [&](size_t bytes)->char*{
        char* p = base + off_b;
        off_b += (bytes + 255) & ~(size_t)255;
        return p;
    };
    float* vecs = (float*)alloc(1280*4);
    u16*   Wf   = (u16*)  alloc(5*16384*2);
    float* el1 = (float*)alloc(N_K*4);
    float* el2 = (float*)alloc(N_E*4);
    float* el3 = (float*)alloc(N_K*4);
    float* el4 = (float*)alloc(N_E*4);
    float* el5 = (float*)alloc(N_U*4);
    float* erc = (float*)alloc((size_t)N_TOT*4);
    int* cnt  = (int*)alloc((size_t)N_TOT*4);
    int* offA = (int*)alloc((size_t)N_TOT*4);
    int* btot = (int*)alloc(NBKT*4);
    int* bbase= (int*)alloc(NBKT*4);
    int* hist = (int*)alloc((size_t)NBKT*APAD*4);
    uint2* rec = (uint2*)alloc((size_t)E_TOT*8);
    float* evb = (float*)alloc((size_t)E_TOT*4);
    int2* sorted2 = (int2*)alloc((size_t)E_TOT*8);   // {src, alpha}
    u16* knb   = (u16*)alloc((size_t)N_K*128*2);
    u16* exerb = (u16*)alloc((size_t)N_E*128*2);
    u16* stub  = (u16*)alloc((size_t)N_U*128*2);
    u8* knf   = (u8*)alloc((size_t)N_K*128);
    u8* exerf = (u8*)alloc((size_t)N_E*128);
    u8* stuf  = (u8*)alloc((size_t)N_U*128);
    size_t need_bf = off_b;
    bool useBF = (ws_size >= need_bf);
    float* out = (float*)d_out;

    prep_w<<<360,256,0,stream>>>(W_und,W_ek,W_ke,W_eu,W_ue, a_und,a_ek,a_ke,a_eu,a_ue, vecs, Wf);

    if (useBF)
        conv_all<1><<<(170000+3)/4,256,0,stream>>>(kn, exer, stu, knb, exerb, stub,
                                                   knf, exerf, stuf, vecs,
                                                   el1, el2, el3, el4, el5, erc);
    else
        conv_all<0><<<(170000+3)/4,256,0,stream>>>(kn, exer, stu, knb, exerb, stub,
                                                   knf, exerf, stuf, vecs,
                                                   el1, el2, el3, el4, el5, erc);

    bkt_hist<<<NBLKA,256,0,stream>>>(und_dst, ek_src, ek_dst, eu_src, eu_dst, hist);
    bkt_scan1<<<NBKT,512,0,stream>>>(hist, btot);
    bkt_scan2<<<1,1024,0,stream>>>(btot, bbase);
    bkt_scatter<<<NBLKA,256,0,stream>>>(und_src, und_dst, ek_src, ek_dst, eu_src, eu_dst,
                                        hist, bbase, rec);
    bkt_finalize<<<NBKT,512,0,stream>>>(rec, bbase, btot, erc,
                                        el1, el2, el3, el4, el5, evb,
                                        cnt, offA, sorted2);

    if (useBF){
        agg_gemm_epi<1><<<KN_B+EX_B+ST_B,256,0,stream>>>(cnt, offA, sorted2,
            knf, exerf, stuf, knb, exerb, stub, Wf,
            kfc2w,kfc2b,kfc3w,kfc3b, efc1w,efc1b,efc2w,efc2b, out);
    } else {
        agg_gemm_epi<0><<<KN_B+EX_B+ST_B,256,0,stream>>>(cnt, offA, sorted2,
            kn, exer, stu, kn, exer, stu, Wf,
            kfc2w,kfc2b,kfc3w,kfc3b, efc1w,efc1b,efc2w,efc2b, out);
    }
}

// Round 11
// 286.002 us; speedup vs baseline: 1.5248x; 1.0468x over previous
//
#include <hip/hip_runtime.h>

#define N_K 20000
#define N_E 50000
#define N_U 100000
#define E_TOT 2200000
#define N_TOT 240000
// key-space (concat dst) bases
#define KB1 0
#define KB2 20000
#define KB3 40000
#define KB4 90000
#define KB5 190000
// bucket sort geometry
#define NBKT 726
#define EPB 8192
#define NBLKA 269          // ceil(E_TOT / EPB)
#define APAD 272
// fused agg+gemm block counts (16 nodes per block)
#define KN_B 1250
#define EX_B 3125
#define ST_B 6250

typedef unsigned short u16;
typedef unsigned int u32;
typedef __bf16 bf16x8 __attribute__((ext_vector_type(8)));
typedef float f32x4 __attribute__((ext_vector_type(4)));

__device__ __forceinline__ float bf2f(u16 v){
    union { u32 u; float f; } x; x.u = ((u32)v) << 16; return x.f;
}
__device__ __forceinline__ u16 f2bf(float f){
    union { float f; u32 u; } x; x.f = f;
    u32 r = x.u + 0x7FFFu + ((x.u >> 16) & 1u);
    return (u16)(r >> 16);
}
__device__ __forceinline__ float leaky_exp(float x){
    x = x >= 0.f ? x : 0.01f*x;
    return __expf(x);
}

// bucket mapping: per-range shifts, each bucket <=512 keys
__device__ __forceinline__ int bucket_of(int key){
    if (key < 20000)  return key >> 8;
    if (key < 40000)  return 79  + ((key - 20000) >> 7);
    if (key < 90000)  return 236 + ((key - 40000) >> 9);
    if (key < 190000) return 334 + ((key - 90000) >> 9);
    return 530 + ((key - 190000) >> 8);
}
__device__ __forceinline__ void bucket_info(int b, int& kb, int& w, int& r){
    if (b < 79){       r=0; kb = b << 8;                 w = min(256, 20000  - kb); }
    else if (b < 236){ r=1; kb = 20000 + ((b-79)  << 7); w = min(128, 40000  - kb); }
    else if (b < 334){ r=2; kb = 40000 + ((b-236) << 9); w = min(512, 90000  - kb); }
    else if (b < 530){ r=3; kb = 90000 + ((b-334) << 9); w = min(512, 190000 - kb); }
    else {             r=4; kb = 190000 + ((b-530) << 8); w = min(256, 240000 - kb); }
}
__device__ __forceinline__ int edge_key(int e,
    const int* ud, const int* es, const int* ed, const int* vs, const int* vd){
    if (e < 200000)  return ud[e];
    if (e < 600000)  return 20000  + ed[e-200000];
    if (e < 1000000) return 40000  + es[e-600000];
    if (e < 1600000) return 90000  + vd[e-1000000];
    return 190000 + vs[e-1600000];
}
__device__ __forceinline__ int edge_src(int e,
    const int* us, const int* es, const int* ed, const int* vs, const int* vd){
    if (e < 200000)  return us[e];
    if (e < 600000)  return es[e-200000];
    if (e < 1000000) return ed[e-600000];
    if (e < 1600000) return vs[e-1000000];
    return vd[e-1600000];
}

// ------------------------------------------------- fused weight prep (vecs + MFMA frags)
__global__ __launch_bounds__(256) void prep_w(
    const float* W0, const float* W1, const float* W2, const float* W3, const float* W4,
    const float* a0, const float* a1, const float* a2, const float* a3, const float* a4,
    float* __restrict__ vecs, u16* __restrict__ Wf)
{
    int bid = blockIdx.x;
    if (bid < 320){
        int o = bid*4 + (threadIdx.x >> 6);
        int lane = threadIdx.x & 63;
        int which = o / 640, rem = o - which*640, g = rem >> 7, k = rem & 127;
        const float* W = g==0?W0:g==1?W1:g==2?W2:g==3?W3:W4;
        const float* a = g==0?a0:g==1?a1:g==2?a2:g==3?a3:a4;
        const float* av = a + which*128;
        int c = lane*2;
        float s = W[k*128 + c]*av[c] + W[k*128 + c + 1]*av[c+1];
        #pragma unroll
        for (int m = 32; m; m >>= 1) s += __shfl_xor(s, m);
        if (lane == 0) vecs[(which*5 + g)*128 + k] = s;
    } else {
        int t = (bid - 320)*256 + threadIdx.x;   // 0..10239
        int g = t / 2048, i = t - g*2048;
        const float* W = g==0?W0:g==1?W1:g==2?W2:g==3?W3:W4;
        int lane = i & 63, tt = i >> 6, ks = tt & 3, ct = tt >> 2;
        int kbase = ks*32 + (lane>>4)*8;
        int c = ct*16 + (lane&15);
        #pragma unroll
        for (int j = 0; j < 8; ++j)
            Wf[g*16384 + i*8 + j] = f2bf(W[(kbase+j)*128 + c]);
    }
}

// ------------------------------------------------- fused conv(f32->bf16) + row dots
template<int WBF>
__global__ __launch_bounds__(256) void conv_all(
    const float* __restrict__ kn, const float* __restrict__ exer, const float* __restrict__ stu,
    u16* __restrict__ knb, u16* __restrict__ exerb, u16* __restrict__ stub,
    const float* __restrict__ vecs,
    float* __restrict__ el1, float* __restrict__ el2, float* __restrict__ el3,
    float* __restrict__ el4, float* __restrict__ el5, float* __restrict__ erc)
{
    int w = (int)((blockIdx.x*(u32)blockDim.x + threadIdx.x) >> 6);
    int lane = threadIdx.x & 63;
    if (w >= 170000) return;
    const float* h; u16* hb; int local, nd;
    const float *v0,*v1,*v2,*v3;
    float *o0,*o1,*o2,*o3;
    if (w < 20000){
        local = w; h = kn; hb = knb; nd = 4;
        v0=vecs+0;    v1=vecs+640;  v2=vecs+768;  v3=vecs+256;
        o0=el1; o1=erc+KB1; o2=erc+KB2; o3=el3;
    } else if (w < 70000){
        local = w - 20000; h = exer; hb = exerb; nd = 4;
        v0=vecs+128;  v1=vecs+896;  v2=vecs+384;  v3=vecs+1152;
        o0=el2; o1=erc+KB3; o2=el4; o3=erc+KB5;
    } else {
        local = w - 70000; h = stu; hb = stub; nd = 2;
        v0=vecs+1024; v1=vecs+512;  v2=vecs;      v3=vecs;
        o0=erc+KB4; o1=el5; o2=nullptr; o3=nullptr;
    }
    float2 hv = *(const float2*)(h + (size_t)local*128 + lane*2);
    if (WBF)
        *(u32*)(hb + (size_t)local*128 + lane*2) = (u32)f2bf(hv.x) | ((u32)f2bf(hv.y) << 16);
    int c = lane*2;
    float d0 = hv.x*v0[c] + hv.y*v0[c+1];
    float d1 = hv.x*v1[c] + hv.y*v1[c+1];
    float d2 = hv.x*v2[c] + hv.y*v2[c+1];
    float d3 = hv.x*v3[c] + hv.y*v3[c+1];
    #pragma unroll
    for (int o = 32; o; o >>= 1){
        d0 += __shfl_xor(d0, o); d1 += __shfl_xor(d1, o);
        d2 += __shfl_xor(d2, o); d3 += __shfl_xor(d3, o);
    }
    if (lane == 0){
        o0[local] = d0; o1[local] = d1;
        if (nd == 4){ o2[local] = d2; o3[local] = d3; }
    }
}

// ------------------------------------------------- atomic-free CSR build
__global__ __launch_bounds__(256) void bkt_hist(
    const int* __restrict__ ud, const int* __restrict__ es, const int* __restrict__ ed,
    const int* __restrict__ vs, const int* __restrict__ vd, int* __restrict__ hist)
{
    __shared__ int h[NBKT];
    for (int i = threadIdx.x; i < NBKT; i += 256) h[i] = 0;
    __syncthreads();
    int base = blockIdx.x * EPB;
    #pragma unroll 4
    for (int it = 0; it < EPB/256; ++it){
        int e = base + it*256 + threadIdx.x;
        if (e < E_TOT){
            int key = edge_key(e, ud, es, ed, vs, vd);
            atomicAdd(&h[bucket_of(key)], 1);
        }
    }
    __syncthreads();
    for (int i = threadIdx.x; i < NBKT; i += 256)
        hist[i*APAD + blockIdx.x] = h[i];
}

__global__ __launch_bounds__(512) void bkt_scan1(int* __restrict__ hist, int* __restrict__ btot)
{
    __shared__ int sm[512];
    int t = threadIdx.x;
    int v = (t < NBLKA) ? hist[blockIdx.x*APAD + t] : 0;
    sm[t] = v; __syncthreads();
    #pragma unroll
    for (int d = 1; d < 512; d <<= 1){
        int x = (t >= d) ? sm[t-d] : 0;
        __syncthreads();
        sm[t] += x;
        __syncthreads();
    }
    if (t < NBLKA) hist[blockIdx.x*APAD + t] = sm[t] - v;
    if (t == 511) btot[blockIdx.x] = sm[511];
}

__global__ __launch_bounds__(1024) void bkt_scan2(const int* __restrict__ btot, int* __restrict__ bbase)
{
    __shared__ int sm[1024];
    int t = threadIdx.x;
    int v = (t < NBKT) ? btot[t] : 0;
    sm[t] = v; __syncthreads();
    #pragma unroll
    for (int d = 1; d < 1024; d <<= 1){
        int x = (t >= d) ? sm[t-d] : 0;
        __syncthreads();
        sm[t] += x;
        __syncthreads();
    }
    if (t < NBKT) bbase[t] = sm[t] - v;
}

__global__ __launch_bounds__(256) void bkt_scatter(
    const int* __restrict__ us, const int* __restrict__ ud,
    const int* __restrict__ es, const int* __restrict__ ed,
    const int* __restrict__ vs, const int* __restrict__ vd,
    const int* __restrict__ hist, const int* __restrict__ bbase,
    uint2* __restrict__ rec)
{
    __shared__ int cur[NBKT];
    for (int i = threadIdx.x; i < NBKT; i += 256)
        cur[i] = bbase[i] + hist[i*APAD + blockIdx.x];
    __syncthreads();
    int base = blockIdx.x * EPB;
    #pragma unroll 4
    for (int it = 0; it < EPB/256; ++it){
        int e = base + it*256 + threadIdx.x;
        if (e < E_TOT){
            int key = edge_key(e, ud, es, ed, vs, vd);
            int src = edge_src(e, us, es, ed, vs, vd);
            int pos = atomicAdd(&cur[bucket_of(key)], 1);
            rec[pos] = make_uint2((u32)src, (u32)key);
        }
    }
}

// per-bucket: key hist + ev-sum -> cnt/offA (bbase + LDS scan), then place
// {src, alpha=ev/sum}. Pass 1 caches ev in evb so pass 2 skips el re-gather + exp.
__global__ __launch_bounds__(512) void bkt_finalize(const uint2* __restrict__ rec,
    const int* __restrict__ bbase, const int* __restrict__ btot,
    const float* __restrict__ erc,
    const float* __restrict__ el1, const float* __restrict__ el2,
    const float* __restrict__ el3, const float* __restrict__ el4,
    const float* __restrict__ el5, float* __restrict__ evb,
    int* __restrict__ cnt, int* __restrict__ offA, int2* __restrict__ sorted2)
{
    __shared__ int   h[512];
    __shared__ float s[512];
    __shared__ float ercs[512];
    __shared__ int   sm[512];
    __shared__ int   curk[512];
    int b = blockIdx.x, t = threadIdx.x;
    int kb, w, r;
    bucket_info(b, kb, w, r);
    h[t] = 0; s[t] = 0.f;
    if (t < w) ercs[t] = erc[kb + t];
    __syncthreads();
    const float* el = r==0?el1 : r==1?el2 : r==2?el3 : r==3?el4 : el5;
    int start = bbase[b], n = btot[b];
    for (int i = t; i < n; i += 512){
        uint2 rc = rec[start + i];
        int local = (int)rc.y - kb;
        float ev = leaky_exp(el[rc.x] + ercs[local]);
        evb[start + i] = ev;
        atomicAdd(&h[local], 1);
        atomicAdd(&s[local], ev);
    }
    __syncthreads();
    int hv = h[t];
    if (t < w) cnt[kb + t] = hv;
    sm[t] = hv; __syncthreads();
    #pragma unroll
    for (int d = 1; d < 512; d <<= 1){
        int x = (t >= d) ? sm[t-d] : 0;
        __syncthreads();
        sm[t] += x;
        __syncthreads();
    }
    int pos0 = start + sm[t] - hv;
    if (t < w) offA[kb + t] = pos0;
    curk[t] = pos0;
    __syncthreads();
    for (int i = t; i < n; i += 512){
        uint2 rc = rec[start + i];
        int local = (int)rc.y - kb;
        float alpha = evb[start + i] / s[local];
        int pos = atomicAdd(&curk[local], 1);
        sorted2[pos] = make_int2((int)rc.x, __float_as_int(alpha));
    }
}

// ------------------------------------------------- fused aggregation + dual-GEMM + epilogue
// Aggregation is latency-bound (r10: halving gather bytes changed nothing) ->
// 2-stream pairs: each wave processes rows in pairs with two independent
// {deg/start -> sorted2 -> gather} chains interleaved (2x requests in flight).
template<int BF>
__global__ __launch_bounds__(256) void agg_gemm_epi(
    const int* __restrict__ cnt, const int* __restrict__ offA, const int2* __restrict__ sorted2,
    const void* __restrict__ hk, const void* __restrict__ he, const void* __restrict__ hs,
    const u16* __restrict__ Wf,
    const float* __restrict__ kfc2w, const float* __restrict__ kfc2b,
    const float* __restrict__ kfc3w, const float* __restrict__ kfc3b,
    const float* __restrict__ efc1w, const float* __restrict__ efc1b,
    const float* __restrict__ efc2w, const float* __restrict__ efc2b,
    float* __restrict__ out)
{
    __shared__ u16 ldsC[16*136];
    __shared__ u16 ldsD[16*136];
    __shared__ float sred2[16], sred3[16], p2s[16], p3s[16];

    int bid = blockIdx.x;
    int wave = threadIdx.x >> 6, lane = threadIdx.x & 63;
    int kind, node0, keyC, keyD;
    const void *hC, *hD, *Aseg;
    const u16 *wc, *wd;
    const float *w2, *b2, *w3, *b3;
    float* outp;
    if (bid < KN_B){
        kind=0; node0 = bid*16;
        keyC = KB1 + node0; keyD = KB2 + node0;
        hC = hk; hD = he; Aseg = hk;
        wc = Wf; wd = Wf + 16384;
        w2=kfc2w; b2=kfc2b; w3=kfc3w; b3=kfc3b;
        outp = out;
    } else if (bid < KN_B + EX_B){
        kind=0; node0 = (bid - KN_B)*16;
        keyC = KB3 + node0; keyD = KB5 + node0;
        hC = hk; hD = hs; Aseg = he;
        wc = Wf + 2*16384; wd = Wf + 4*16384;
        w2=efc1w; b2=efc1b; w3=efc2w; b3=efc2b;
        outp = out + (size_t)N_K*128;
    } else {
        kind=1; node0 = (bid - KN_B - EX_B)*16;
        keyC = KB4 + node0; keyD = 0;
        hC = he; hD = nullptr; Aseg = hs;
        wc = Wf + 3*16384; wd = nullptr;
        w2=nullptr; b2=nullptr; w3=nullptr; b3=nullptr;
        outp = out + (size_t)(N_K + N_E)*128;
    }

    // ---- aggregation into LDS: 2-stream pairs ----
    int rpw = (kind == 0) ? 8 : 4;
    for (int rr = 0; rr < rpw; rr += 2){
        int cA = wave*rpw + rr;                 // even -> pair stays in one seg
        int seg = cA >> 4, ndA = cA & 15;
        int keyA = (seg == 0 ? keyC : keyD) + ndA;
        const u32* hb32 = (const u32*)(seg == 0 ? hC : hD);
        const float2* hf2 = (const float2*)(seg == 0 ? hC : hD);
        int degA = cnt[keyA],     startA = offA[keyA];
        int degB = cnt[keyA + 1], startB = offA[keyA + 1];
        float a0A=0.f, a1A=0.f, a0B=0.f, a1B=0.f;
        int iA = 0, iB = 0;
        // merged main loop: 4-deep per stream, 8 gathers in flight
        while (iA + 4 <= degA && iB + 4 <= degB){
            int2 wA[4], wB[4];
            #pragma unroll
            for (int j = 0; j < 4; ++j){
                wA[j] = sorted2[startA + iA + j];
                wB[j] = sorted2[startB + iB + j];
            }
            if (BF){
                u32 hvA[4], hvB[4];
                #pragma unroll
                for (int j = 0; j < 4; ++j){
                    hvA[j] = hb32[(size_t)wA[j].x*64 + lane];
                    hvB[j] = hb32[(size_t)wB[j].x*64 + lane];
                }
                #pragma unroll
                for (int j = 0; j < 4; ++j){
                    float alA = __int_as_float(wA[j].y);
                    float alB = __int_as_float(wB[j].y);
                    a0A = fmaf(alA, bf2f((u16)hvA[j]), a0A);
                    a1A = fmaf(alA, bf2f((u16)(hvA[j]>>16)), a1A);
                    a0B = fmaf(alB, bf2f((u16)hvB[j]), a0B);
                    a1B = fmaf(alB, bf2f((u16)(hvB[j]>>16)), a1B);
                }
            } else {
                float2 hvA[4], hvB[4];
                #pragma unroll
                for (int j = 0; j < 4; ++j){
                    hvA[j] = hf2[(size_t)wA[j].x*64 + lane];
                    hvB[j] = hf2[(size_t)wB[j].x*64 + lane];
                }
                #pragma unroll
                for (int j = 0; j < 4; ++j){
                    float alA = __int_as_float(wA[j].y);
                    float alB = __int_as_float(wB[j].y);
                    a0A = fmaf(alA, hvA[j].x, a0A); a1A = fmaf(alA, hvA[j].y, a1A);
                    a0B = fmaf(alB, hvB[j].x, a0B); a1B = fmaf(alB, hvB[j].y, a1B);
                }
            }
            iA += 4; iB += 4;
        }
        // drain whichever stream still has >=4
        for (; iA + 4 <= degA; iA += 4){
            int2 w[4];
            #pragma unroll
            for (int j = 0; j < 4; ++j) w[j] = sorted2[startA + iA + j];
            if (BF){
                u32 hv[4];
                #pragma unroll
                for (int j = 0; j < 4; ++j) hv[j] = hb32[(size_t)w[j].x*64 + lane];
                #pragma unroll
                for (int j = 0; j < 4; ++j){
                    float al = __int_as_float(w[j].y);
                    a0A = fmaf(al, bf2f((u16)hv[j]), a0A);
                    a1A = fmaf(al, bf2f((u16)(hv[j]>>16)), a1A);
                }
            } else {
                float2 hv[4];
                #pragma unroll
                for (int j = 0; j < 4; ++j) hv[j] = hf2[(size_t)w[j].x*64 + lane];
                #pragma unroll
                for (int j = 0; j < 4; ++j){
                    float al = __int_as_float(w[j].y);
                    a0A = fmaf(al, hv[j].x, a0A); a1A = fmaf(al, hv[j].y, a1A);
                }
            }
        }
        for (; iB + 4 <= degB; iB += 4){
            int2 w[4];
            #pragma unroll
            for (int j = 0; j < 4; ++j) w[j] = sorted2[startB + iB + j];
            if (BF){
                u32 hv[4];
                #pragma unroll
                for (int j = 0; j < 4; ++j) hv[j] = hb32[(size_t)w[j].x*64 + lane];
                #pragma unroll
                for (int j = 0; j < 4; ++j){
                    float al = __int_as_float(w[j].y);
                    a0B = fmaf(al, bf2f((u16)hv[j]), a0B);
                    a1B = fmaf(al, bf2f((u16)(hv[j]>>16)), a1B);
                }
            } else {
                float2 hv[4];
                #pragma unroll
                for (int j = 0; j < 4; ++j) hv[j] = hf2[(size_t)w[j].x*64 + lane];
                #pragma unroll
                for (int j = 0; j < 4; ++j){
                    float al = __int_as_float(w[j].y);
                    a0B = fmaf(al, hv[j].x, a0B); a1B = fmaf(al, hv[j].y, a1B);
                }
            }
        }
        // interleaved singles (wave-uniform conditions)
        while (iA < degA || iB < degB){
            bool dA = iA < degA, dB = iB < degB;
            int2 wA, wB;
            if (dA) wA = sorted2[startA + iA];
            if (dB) wB = sorted2[startB + iB];
            if (BF){
                u32 hvA = 0, hvB = 0;
                if (dA) hvA = hb32[(size_t)wA.x*64 + lane];
                if (dB) hvB = hb32[(size_t)wB.x*64 + lane];
                if (dA){
                    float al = __int_as_float(wA.y);
                    a0A = fmaf(al, bf2f((u16)hvA), a0A);
                    a1A = fmaf(al, bf2f((u16)(hvA>>16)), a1A);
                    ++iA;
                }
                if (dB){
                    float al = __int_as_float(wB.y);
                    a0B = fmaf(al, bf2f((u16)hvB), a0B);
                    a1B = fmaf(al, bf2f((u16)(hvB>>16)), a1B);
                    ++iB;
                }
            } else {
                float2 hvA = make_float2(0.f,0.f), hvB = make_float2(0.f,0.f);
                if (dA) hvA = hf2[(size_t)wA.x*64 + lane];
                if (dB) hvB = hf2[(size_t)wB.x*64 + lane];
                if (dA){
                    float al = __int_as_float(wA.y);
                    a0A = fmaf(al, hvA.x, a0A); a1A = fmaf(al, hvA.y, a1A);
                    ++iA;
                }
                if (dB){
                    float al = __int_as_float(wB.y);
                    a0B = fmaf(al, hvB.x, a0B); a1B = fmaf(al, hvB.y, a1B);
                    ++iB;
                }
            }
        }
        u16* ldsSeg = (seg == 0 ? ldsC : ldsD);
        *(u32*)(ldsSeg + ndA*136 + lane*2)     = (u32)f2bf(a0A) | ((u32)f2bf(a1A) << 16);
        *(u32*)(ldsSeg + (ndA+1)*136 + lane*2) = (u32)f2bf(a0B) | ((u32)f2bf(a1B) << 16);
    }
    if (threadIdx.x < 16){ sred2[threadIdx.x] = 0.f; sred3[threadIdx.x] = 0.f; }
    __syncthreads();

    // ---- GEMM phase: wave handles ct = 2*wave, 2*wave+1 ----
    int colb = lane & 15, rlo = (lane >> 4)*4;
    const float* Af = (const float*)Aseg;
    const u16*   Ab = (const u16*)Aseg;

    bf16x8 afC[4];
    #pragma unroll
    for (int ks = 0; ks < 4; ++ks)
        afC[ks] = *(const bf16x8*)(ldsC + (lane & 15)*136 + ks*32 + (lane >> 4)*8);
    f32x4 accC[2];
    accC[0] = (f32x4){0.f,0.f,0.f,0.f}; accC[1] = (f32x4){0.f,0.f,0.f,0.f};
    #pragma unroll
    for (int ci = 0; ci < 2; ++ci){
        int ct = wave*2 + ci;
        #pragma unroll
        for (int ks = 0; ks < 4; ++ks){
            bf16x8 bfr = *(const bf16x8*)(wc + ((ct*4+ks)*64 + lane)*8);
            accC[ci] = __builtin_amdgcn_mfma_f32_16x16x32_bf16(afC[ks], bfr, accC[ci], 0, 0, 0);
        }
    }

    if (kind == 1){
        #pragma unroll
        for (int ci = 0; ci < 2; ++ci){
            int ct = wave*2 + ci;
            #pragma unroll
            for (int j = 0; j < 4; ++j){
                size_t idx = (size_t)(node0 + rlo + j)*128 + ct*16 + colb;
                float av = BF ? bf2f(Ab[idx]) : Af[idx];
                outp[idx] = accC[ci][j] + av;
            }
        }
        return;
    }

    bf16x8 afD[4];
    #pragma unroll
    for (int ks = 0; ks < 4; ++ks)
        afD[ks] = *(const bf16x8*)(ldsD + (lane & 15)*136 + ks*32 + (lane >> 4)*8);
    f32x4 accD[2];
    accD[0] = (f32x4){0.f,0.f,0.f,0.f}; accD[1] = (f32x4){0.f,0.f,0.f,0.f};
    #pragma unroll
    for (int ci = 0; ci < 2; ++ci){
        int ct = wave*2 + ci;
        #pragma unroll
        for (int ks = 0; ks < 4; ++ks){
            bf16x8 bfr = *(const bf16x8*)(wd + ((ct*4+ks)*64 + lane)*8);
            accD[ci] = __builtin_amdgcn_mfma_f32_16x16x32_bf16(afD[ks], bfr, accD[ci], 0, 0, 0);
        }
    }

    float aA[2][4];
    float s2p[4] = {0.f,0.f,0.f,0.f}, s3p[4] = {0.f,0.f,0.f,0.f};
    #pragma unroll
    for (int ci = 0; ci < 2; ++ci){
        int ct = wave*2 + ci;
        float w2l = w2[ct*16 + colb], w2h = w2[128 + ct*16 + colb];
        float w3l = w3[ct*16 + colb], w3h = w3[128 + ct*16 + colb];
        #pragma unroll
        for (int j = 0; j < 4; ++j){
            size_t idx = (size_t)(node0 + rlo + j)*128 + ct*16 + colb;
            float av = BF ? bf2f(Ab[idx]) : Af[idx];
            aA[ci][j] = av;
            s2p[j] = fmaf(av, w2l, fmaf(accC[ci][j], w2h, s2p[j]));
            s3p[j] = fmaf(av, w3l, fmaf(accD[ci][j], w3h, s3p[j]));
        }
    }
    #pragma unroll
    for (int m = 8; m; m >>= 1)
        #pragma unroll
        for (int j = 0; j < 4; ++j){
            s2p[j] += __shfl_xor(s2p[j], m);
            s3p[j] += __shfl_xor(s3p[j], m);
        }
    if (colb == 0){
        #pragma unroll
        for (int j = 0; j < 4; ++j){
            atomicAdd(&sred2[rlo + j], s2p[j]);
            atomicAdd(&sred3[rlo + j], s3p[j]);
        }
    }
    __syncthreads();
    if (threadIdx.x < 16){
        float s2 = sred2[threadIdx.x] + b2[0];
        float s3 = sred3[threadIdx.x] + b3[0];
        float mx = fmaxf(s2, s3);
        float e2 = __expf(s2 - mx), e3 = __expf(s3 - mx);
        float inv = 1.f/(e2 + e3);
        p2s[threadIdx.x] = e2*inv;
        p3s[threadIdx.x] = e3*inv;
    }
    __syncthreads();
    #pragma unroll
    for (int ci = 0; ci < 2; ++ci){
        int ct = wave*2 + ci;
        #pragma unroll
        for (int j = 0; j < 4; ++j){
            int row = rlo + j;
            size_t idx = (size_t)(node0 + row)*128 + ct*16 + colb;
            outp[idx] = aA[ci][j] + p2s[row]*accC[ci][j] + p3s[row]*accD[ci][j];
        }
    }
}

extern "C" void kernel_launch(void* const* d_in, const int* in_sizes, int n_in,
                              void* d_out, int out_size, void* d_ws, size_t ws_size,
                              hipStream_t stream)
{
    (void)in_sizes; (void)n_in; (void)out_size;
    const float* kn   = (const float*)d_in[0];
    const float* exer = (const float*)d_in[1];
    const float* stu  = (const float*)d_in[2];
    const int* und_src = (const int*)d_in[3];
    const int* und_dst = (const int*)d_in[4];
    const int* ek_src  = (const int*)d_in[5];
    const int* ek_dst  = (const int*)d_in[6];
    const int* eu_src  = (const int*)d_in[7];
    const int* eu_dst  = (const int*)d_in[8];
    const float* W_und = (const float*)d_in[9];  const float* a_und = (const float*)d_in[10];
    const float* W_ek  = (const float*)d_in[11]; const float* a_ek  = (const float*)d_in[12];
    const float* W_ke  = (const float*)d_in[13]; const float* a_ke  = (const float*)d_in[14];
    const float* W_eu  = (const float*)d_in[15]; const float* a_eu  = (const float*)d_in[16];
    const float* W_ue  = (const float*)d_in[17]; const float* a_ue  = (const float*)d_in[18];
    const float* kfc2w = (const float*)d_in[19]; const float* kfc2b = (const float*)d_in[20];
    const float* kfc3w = (const float*)d_in[21]; const float* kfc3b = (const float*)d_in[22];
    const float* efc1w = (const float*)d_in[23]; const float* efc1b = (const float*)d_in[24];
    const float* efc2w = (const float*)d_in[25]; const float* efc2b = (const float*)d_in[26];

    char* base = (char*)d_ws;
    size_t off_b = 0;
    auto alloc = [&](size_t bytes)->char*{
        char* p = base + off_b;
        off_b += (bytes + 255) & ~(size_t)255;
        return p;
    };
    float* vecs = (float*)alloc(1280*4);
    u16*   Wf   = (u16*)  alloc(5*16384*2);
    float* el1 = (float*)alloc(N_K*4);
    float* el2 = (float*)alloc(N_E*4);
    float* el3 = (float*)alloc(N_K*4);
    float* el4 = (float*)alloc(N_E*4);
    float* el5 = (float*)alloc(N_U*4);
    float* erc = (float*)alloc((size_t)N_TOT*4);
    int* cnt  = (int*)alloc((size_t)N_TOT*4);
    int* offA = (int*)alloc((size_t)N_TOT*4);
    int* btot = (int*)alloc(NBKT*4);
    int* bbase= (int*)alloc(NBKT*4);
    int* hist = (int*)alloc((size_t)NBKT*APAD*4);
    uint2* rec = (uint2*)alloc((size_t)E_TOT*8);
    float* evb = (float*)alloc((size_t)E_TOT*4);
    int2* sorted2 = (int2*)alloc((size_t)E_TOT*8);   // {src, alpha}
    u16* knb   = (u16*)alloc((size_t)N_K*128*2);
    u16* exerb = (u16*)alloc((size_t)N_E*128*2);
    u16* stub  = (u16*)alloc((size_t)N_U*128*2);
    size_t need_bf = off_b;
    bool useBF = (ws_size >= need_bf);
    float* out = (float*)d_out;

    prep_w<<<360,256,0,stream>>>(W_und,W_ek,W_ke,W_eu,W_ue, a_und,a_ek,a_ke,a_eu,a_ue, vecs, Wf);

    if (useBF)
        conv_all<1><<<(170000+3)/4,256,0,stream>>>(kn, exer, stu, knb, exerb, stub, vecs,
                                                   el1, el2, el3, el4, el5, erc);
    else
        conv_all<0><<<(170000+3)/4,256,0,stream>>>(kn, exer, stu, knb, exerb, stub, vecs,
                                                   el1, el2, el3, el4, el5, erc);

    bkt_hist<<<NBLKA,256,0,stream>>>(und_dst, ek_src, ek_dst, eu_src, eu_dst, hist);
    bkt_scan1<<<NBKT,512,0,stream>>>(hist, btot);
    bkt_scan2<<<1,1024,0,stream>>>(btot, bbase);
    bkt_scatter<<<NBLKA,256,0,stream>>>(und_src, und_dst, ek_src, ek_dst, eu_src, eu_dst,
                                        hist, bbase, rec);
    bkt_finalize<<<NBKT,512,0,stream>>>(rec, bbase, btot, erc,
                                        el1, el2, el3, el4, el5, evb,
                                        cnt, offA, sorted2);

    if (useBF){
        agg_gemm_epi<1><<<KN_B+EX_B+ST_B,256,0,stream>>>(cnt, offA, sorted2,
            knb, exerb, stub, Wf,
            kfc2w,kfc2b,kfc3w,kfc3b, efc1w,efc1b,efc2w,efc2b, out);
    } else {
        agg_gemm_epi<0><<<KN_B+EX_B+ST_B,256,0,stream>>>(cnt, offA, sorted2,
            kn, exer, stu, Wf,
            kfc2w,kfc2b,kfc3w,kfc3b, efc1w,efc1b,efc2w,efc2b, out);
    }
}